// Round 10
// baseline (620.727 us; speedup 1.0000x reference)
//
#include <hip/hip_runtime.h>
#include <stdint.h>

// HashEmbedder (Instant-NGP multires hash grid), 16 levels, F=2, T=2^19,
// N = 2^21 points.
//
// Round-10: fine_kernel gathers issued via INLINE-ASM global_load +
// hand-counted s_waitcnt vmcnt(N) (AITER/T4 technique). Rounds 7-9 showed
// hipcc serializes any visible load pipeline (r7: arrays->scratch; r8:
// loads sunk to uses, VGPR=24; r9: sched_barrier defeated by control-flow
// seams). asm volatile loads cannot be sunk/serialized. Structure is
// straight-line branch-free: preload x (compiler VMEM confined to
// prologue so its waitcnt insertion can't drain the pipeline), wall,
// 32 asm gathers (4 pts x [4x dwordx2 pair + 4x dword scalar]), then
// consume ladder vmcnt(24/16/8/0) with sched_barrier(0) fences (rule 18).
// Values bit-identical to rounds 5-9.
//
//   pass 0 : pack f32 tables -> bf16x2.
//   pass 0b: dense tables levels 0-2 (124 KB), dense-x4 levels 3-6.
//   pass A : levels 0-2 via LDS.      pass B : levels 3-6 via dense-x4.
//   pass C : levels 7-15 hashed, level-at-a-time, asm-pipelined.
//   pass 2 : transpose level-major bf16x2 -> [N][32] f32.

constexpr int kLevels = 16;
constexpr int kPoints = 1 << 21;
constexpr uint32_t kTableSize = 1u << 19;
constexpr uint32_t kMask = kTableSize - 1u;
constexpr size_t kPackedBytes = (size_t)kLevels * kTableSize * 4;  // 32 MB
constexpr size_t kLvlOutBytes = (size_t)kLevels * kPoints * 4;     // 128 MB

typedef float f32x4 __attribute__((ext_vector_type(4)));
typedef uint32_t u32x4 __attribute__((ext_vector_type(4)));

// dense coarse (levels 0-2): entry counts and bases (uint32 units)
constexpr int kS0 = 17, kS1 = 21, kS2 = 26;            // res+1
constexpr int kN0 = kS0 * kS0 * kS0;                   // 4913
constexpr int kN1 = kS1 * kS1 * kS1;                   // 9261
constexpr int kN2 = kS2 * kS2 * kS2;                   // 17576
constexpr int kB1 = kN0, kB2 = kN0 + kN1;              // 4913, 14174
constexpr int kNDense = kN0 + kN1 + kN2;               // 31750

// dense-x4 (levels 3-6): group counts (res/2+1)*(res+1)^2
constexpr int kG3 = 17 * 33 * 33;    // 18513
constexpr int kG4 = 21 * 41 * 41;    // 35301
constexpr int kG5 = 26 * 51 * 51;    // 67626
constexpr int kG6 = 33 * 65 * 65;    // 139425
constexpr int kGTot = kG3 + kG4 + kG5 + kG6;           // 260865
constexpr size_t kX4Base3 = 131072;
constexpr size_t kX4Base4 = kX4Base3 + (size_t)kG3 * 16;   // 427280
constexpr size_t kX4Base5 = kX4Base4 + (size_t)kG4 * 16;   // 992096
constexpr size_t kX4Base6 = kX4Base5 + (size_t)kG5 * 16;   // 2074112
// end = 4304912 < 6 MB = packed levels 0-2 region. OK.

// floor(16 * b^i), b = exp(ln(32)/15) in f64 (boundary levels round up).
__constant__ float c_res[kLevels] = {
    16.f, 20.f, 25.f, 32.f, 40.f, 50.f, 64.f, 80.f,
    101.f, 128.f, 161.f, 203.f, 256.f, 322.f, 406.f, 512.f};

__device__ __forceinline__ uint32_t bf16_rtne_hi(float f) {
    uint32_t u = __float_as_uint(f);
    return (u + 0x7FFFu + ((u >> 16) & 1u)) >> 16;
}
__device__ __forceinline__ float bflo(uint32_t e) {
    return __uint_as_float(e << 16);
}
__device__ __forceinline__ float bfhi(uint32_t e) {
    return __uint_as_float(e & 0xFFFF0000u);
}

// ---------------- pass 0: pack tables to bf16x2 ----------------
__global__ __launch_bounds__(256) void pack_tables_kernel(
    const float* __restrict__ tables, uint32_t* __restrict__ packed)
{
    const int i = blockIdx.x * 256 + threadIdx.x;  // 2 entries per thread
    const f32x4 v = reinterpret_cast<const f32x4*>(tables)[i];
    uint2 o;
    o.x = bf16_rtne_hi(v.x) | (bf16_rtne_hi(v.y) << 16);
    o.y = bf16_rtne_hi(v.z) | (bf16_rtne_hi(v.w) << 16);
    reinterpret_cast<uint2*>(packed)[i] = o;
}

// ---------------- pass 0b-1: dense de-hashed tables, levels 0-2 --------
template <int S, int LVL>
__device__ __forceinline__ void build_dense_one(
    int r, const float* __restrict__ tables, uint32_t* __restrict__ dst)
{
    const int bz = r % S;
    const int t = r / S;
    const int by = t % S;
    const int bx = t / S;
    const uint32_t h = ((uint32_t)bx ^ ((uint32_t)by * 2654435761u) ^
                        ((uint32_t)bz * 805459861u)) & kMask;
    const float* src = tables + (((size_t)LVL << 19) + h) * 2;
    dst[r] = bf16_rtne_hi(src[0]) | (bf16_rtne_hi(src[1]) << 16);
}

__global__ __launch_bounds__(256) void build_dense012_kernel(
    const float* __restrict__ tables, uint32_t* __restrict__ dense)
{
    const int idx = blockIdx.x * 256 + threadIdx.x;
    if (idx >= kNDense) return;
    if (idx < kB1)      build_dense_one<kS0, 0>(idx,       tables, dense);
    else if (idx < kB2) build_dense_one<kS1, 1>(idx - kB1, tables, dense + kB1);
    else                build_dense_one<kS2, 2>(idx - kB2, tables, dense + kB2);
}

// ---------------- pass 0b-2: dense-x4 tables, levels 3-6 ----------------
template <int S, int LVL>
__device__ __forceinline__ void build_x4_one(
    int g, const uint32_t* __restrict__ packed, u32x4* __restrict__ dst)
{
    const int bz = g % S;
    const int t = g / S;
    const int by = t % S;
    const int gx = t / S;
    const uint32_t m = ((uint32_t)by * 2654435761u) ^
                       ((uint32_t)bz * 805459861u);
    const uint32_t e = (uint32_t)(gx * 2);
    const uint32_t* tab = packed + ((size_t)LVL << 19);
    u32x4 o;
    o.x = tab[((e + 0) ^ m) & kMask];
    o.y = tab[((e + 1) ^ m) & kMask];
    o.z = tab[((e + 2) ^ m) & kMask];
    o.w = tab[((e + 3) ^ m) & kMask];
    dst[g] = o;
}

__global__ __launch_bounds__(256) void build_x4_kernel(
    const uint32_t* __restrict__ packed, char* __restrict__ ws)
{
    const int g = blockIdx.x * 256 + threadIdx.x;
    if (g >= kGTot) return;
    if (g < kG3)
        build_x4_one<33, 3>(g, packed, (u32x4*)(ws + kX4Base3));
    else if (g < kG3 + kG4)
        build_x4_one<41, 4>(g - kG3, packed, (u32x4*)(ws + kX4Base4));
    else if (g < kG3 + kG4 + kG5)
        build_x4_one<51, 5>(g - kG3 - kG4, packed, (u32x4*)(ws + kX4Base5));
    else
        build_x4_one<65, 6>(g - kG3 - kG4 - kG5, packed, (u32x4*)(ws + kX4Base6));
}

// ---------------- pass A: levels 0-2 via LDS dense tables ----------------
template <int S, int BASE, int LVL>
__device__ __forceinline__ void eval_coarse(
    const uint32_t* __restrict__ lds, float px, float py, float pz, float r,
    uint32_t* __restrict__ lvl_out, int n)
{
    const float tx = px * r, ty = py * r, tz = pz * r;
    const float fx = floorf(tx), fy = floorf(ty), fz = floorf(tz);
    const int bx = (int)fx, by = (int)fy, bz = (int)fz;
    const float rx = tx - fx, ry = ty - fy, rz = tz - fz;
    const int c = BASE + (bx * S + by) * S + bz;
    const uint32_t e000 = lds[c],             e001 = lds[c + 1];
    const uint32_t e010 = lds[c + S],         e011 = lds[c + S + 1];
    const uint32_t e100 = lds[c + S * S],     e101 = lds[c + S * S + 1];
    const uint32_t e110 = lds[c + S * S + S], e111 = lds[c + S * S + S + 1];
    const float wx1 = rx, wx0 = 1.f - rx;
    const float wy1 = ry, wy0 = 1.f - ry;
    const float wz1 = rz, wz0 = 1.f - rz;
    float a0 = 0.f, a1 = 0.f;
    a0 = fmaf(wx0 * wy0 * wz0, bflo(e000), a0);
    a1 = fmaf(wx0 * wy0 * wz0, bfhi(e000), a1);
    a0 = fmaf(wx0 * wy0 * wz1, bflo(e001), a0);
    a1 = fmaf(wx0 * wy0 * wz1, bfhi(e001), a1);
    a0 = fmaf(wx0 * wy1 * wz0, bflo(e010), a0);
    a1 = fmaf(wx0 * wy1 * wz0, bfhi(e010), a1);
    a0 = fmaf(wx0 * wy1 * wz1, bflo(e011), a0);
    a1 = fmaf(wx0 * wy1 * wz1, bfhi(e011), a1);
    a0 = fmaf(wx1 * wy0 * wz0, bflo(e100), a0);
    a1 = fmaf(wx1 * wy0 * wz0, bfhi(e100), a1);
    a0 = fmaf(wx1 * wy0 * wz1, bflo(e101), a0);
    a1 = fmaf(wx1 * wy0 * wz1, bfhi(e101), a1);
    a0 = fmaf(wx1 * wy1 * wz0, bflo(e110), a0);
    a1 = fmaf(wx1 * wy1 * wz0, bfhi(e110), a1);
    a0 = fmaf(wx1 * wy1 * wz1, bflo(e111), a0);
    a1 = fmaf(wx1 * wy1 * wz1, bfhi(e111), a1);
    lvl_out[(size_t)LVL * kPoints + n] =
        bf16_rtne_hi(a0) | (bf16_rtne_hi(a1) << 16);
}

__global__ __launch_bounds__(512) void coarse_kernel(
    const float* __restrict__ x, const uint32_t* __restrict__ dense,
    uint32_t* __restrict__ lvl_out)
{
    __shared__ uint32_t s_tab[kNDense];  // 127000 B
    for (int i = threadIdx.x; i < kNDense; i += 512) s_tab[i] = dense[i];
    __syncthreads();

    const int n0 = blockIdx.x * 2048 + threadIdx.x;
#pragma unroll
    for (int k = 0; k < 4; ++k) {
        const int n = n0 + k * 512;
        const float px = fminf(fmaxf(x[3 * n + 0], 0.0f), 1.0f);
        const float py = fminf(fmaxf(x[3 * n + 1], 0.0f), 1.0f);
        const float pz = fminf(fmaxf(x[3 * n + 2], 0.0f), 1.0f);
        eval_coarse<kS0, 0,   0>(s_tab, px, py, pz, 16.f, lvl_out, n);
        eval_coarse<kS1, kB1, 1>(s_tab, px, py, pz, 20.f, lvl_out, n);
        eval_coarse<kS2, kB2, 2>(s_tab, px, py, pz, 25.f, lvl_out, n);
    }
}

// ---------------- pass B: levels 3-6 via dense-x4 global ----------------
template <int S, int LVL>
__device__ __forceinline__ void eval_mid(
    const u32x4* __restrict__ tab, float px, float py, float pz, float r,
    uint32_t* __restrict__ lvl_out, int n)
{
    const float tx = px * r, ty = py * r, tz = pz * r;
    const float fx = floorf(tx), fy = floorf(ty), fz = floorf(tz);
    const int bx = (int)fx, by = (int)fy, bz = (int)fz;
    const float rx = tx - fx, ry = ty - fy, rz = tz - fz;
    const int gx = bx >> 1;
    const int par = bx & 1;
    const float wx1 = rx, wx0 = 1.f - rx;
    const float wy1 = ry, wy0 = 1.f - ry;
    const float wz1 = rz, wz0 = 1.f - rz;
    float a0 = 0.f, a1 = 0.f;
#pragma unroll
    for (int c = 0; c < 4; ++c) {  // bit1 -> y-corner, bit0 -> z-corner
        const int gidx = (gx * S + (by + ((c >> 1) & 1))) * S + (bz + (c & 1));
        const u32x4 g = tab[gidx];
        const uint32_t lo = par ? g.y : g.x;
        const uint32_t hi = par ? g.z : g.y;
        const float wyz = ((c & 2) ? wy1 : wy0) * ((c & 1) ? wz1 : wz0);
        a0 = fmaf(wyz, fmaf(wx0, bflo(lo), wx1 * bflo(hi)), a0);
        a1 = fmaf(wyz, fmaf(wx0, bfhi(lo), wx1 * bfhi(hi)), a1);
    }
    lvl_out[(size_t)LVL * kPoints + n] =
        bf16_rtne_hi(a0) | (bf16_rtne_hi(a1) << 16);
}

__global__ __launch_bounds__(256) void mid_kernel(
    const float* __restrict__ x, const char* __restrict__ ws,
    uint32_t* __restrict__ lvl_out)
{
    const int b = blockIdx.x;
    const int sub = b >> 11;                 // 0..3 -> level 3..6
    const int chunk = b & 2047;
    const int n0 = chunk * 1024 + threadIdx.x;
#pragma unroll
    for (int k = 0; k < 4; ++k) {
        const int n = n0 + k * 256;
        const float px = fminf(fmaxf(x[3 * n + 0], 0.0f), 1.0f);
        const float py = fminf(fmaxf(x[3 * n + 1], 0.0f), 1.0f);
        const float pz = fminf(fmaxf(x[3 * n + 2], 0.0f), 1.0f);
        if (sub == 0)
            eval_mid<33, 3>((const u32x4*)(ws + kX4Base3), px, py, pz, 32.f, lvl_out, n);
        else if (sub == 1)
            eval_mid<41, 4>((const u32x4*)(ws + kX4Base4), px, py, pz, 40.f, lvl_out, n);
        else if (sub == 2)
            eval_mid<51, 5>((const u32x4*)(ws + kX4Base5), px, py, pz, 50.f, lvl_out, n);
        else
            eval_mid<65, 6>((const u32x4*)(ws + kX4Base6), px, py, pz, 64.f, lvl_out, n);
    }
}

// ------- pass C: levels 7-15 hashed, asm-pipelined gathers --------------
// Per point: 4x global_load_dwordx2 (8B pair at h&~1, contains tab[h] and
// its xor-1 neighbor) + 4x global_load_dword (scalar at high-corner hash).
// sel bit = h&1 picks the pair half. Even-bx scalars land on the pair's
// line (MSHR merge) -> ~6 lines/pt average.

#define FINE_DECL(i)                                                      \
    float rx##i, ry##i, rz##i;                                            \
    uint32_t sel##i;                                                      \
    unsigned long long P##i##0, P##i##1, P##i##2, P##i##3;                \
    uint32_t S##i##0, S##i##1, S##i##2, S##i##3;

#define FINE_ISSUE(i)                                                     \
    {                                                                     \
        const float tx = px##i * r, ty = py##i * r, tz = pz##i * r;       \
        const float fx = floorf(tx), fy = floorf(ty), fz = floorf(tz);    \
        const int bx = (int)fx, by = (int)fy, bz = (int)fz;               \
        rx##i = tx - fx; ry##i = ty - fy; rz##i = tz - fz;                \
        const uint32_t hy0 = (uint32_t)by * 2654435761u;                  \
        const uint32_t hy1 = (uint32_t)(by + 1) * 2654435761u;            \
        const uint32_t hz0 = (uint32_t)bz * 805459861u;                   \
        const uint32_t hz1 = (uint32_t)(bz + 1) * 805459861u;             \
        const uint32_t bxu = (uint32_t)bx, bx1 = bxu + 1u;                \
        const uint32_t m0 = hy0 ^ hz0, m1 = hy0 ^ hz1;                    \
        const uint32_t m2 = hy1 ^ hz0, m3 = hy1 ^ hz1;                    \
        const uint32_t h0 = (bxu ^ m0) & kMask, g0 = (bx1 ^ m0) & kMask;  \
        const uint32_t h1 = (bxu ^ m1) & kMask, g1 = (bx1 ^ m1) & kMask;  \
        const uint32_t h2 = (bxu ^ m2) & kMask, g2 = (bx1 ^ m2) & kMask;  \
        const uint32_t h3 = (bxu ^ m3) & kMask, g3 = (bx1 ^ m3) & kMask;  \
        sel##i = (h0 & 1u) | ((h1 & 1u) << 1) |                           \
                 ((h2 & 1u) << 2) | ((h3 & 1u) << 3);                     \
        asm volatile("global_load_dwordx2 %0, %1, %2"                     \
                     : "=v"(P##i##0) : "v"((h0 & ~1u) << 2), "s"(tab));   \
        asm volatile("global_load_dword %0, %1, %2"                       \
                     : "=v"(S##i##0) : "v"(g0 << 2), "s"(tab));           \
        asm volatile("global_load_dwordx2 %0, %1, %2"                     \
                     : "=v"(P##i##1) : "v"((h1 & ~1u) << 2), "s"(tab));   \
        asm volatile("global_load_dword %0, %1, %2"                       \
                     : "=v"(S##i##1) : "v"(g1 << 2), "s"(tab));           \
        asm volatile("global_load_dwordx2 %0, %1, %2"                     \
                     : "=v"(P##i##2) : "v"((h2 & ~1u) << 2), "s"(tab));   \
        asm volatile("global_load_dword %0, %1, %2"                       \
                     : "=v"(S##i##2) : "v"(g2 << 2), "s"(tab));           \
        asm volatile("global_load_dwordx2 %0, %1, %2"                     \
                     : "=v"(P##i##3) : "v"((h3 & ~1u) << 2), "s"(tab));   \
        asm volatile("global_load_dword %0, %1, %2"                       \
                     : "=v"(S##i##3) : "v"(g3 << 2), "s"(tab));           \
    }

#define FINE_CONSUME(i)                                                   \
    {                                                                     \
        const float wx1 = rx##i, wx0 = 1.f - rx##i;                       \
        const float wy1 = ry##i, wy0 = 1.f - ry##i;                       \
        const float wz1 = rz##i, wz0 = 1.f - rz##i;                       \
        const float w0 = wy0 * wz0, w1 = wy0 * wz1;                       \
        const float w2 = wy1 * wz0, w3 = wy1 * wz1;                       \
        const uint32_t e0 = (sel##i & 1u) ? (uint32_t)(P##i##0 >> 32)     \
                                          : (uint32_t)P##i##0;            \
        const uint32_t e1 = (sel##i & 2u) ? (uint32_t)(P##i##1 >> 32)     \
                                          : (uint32_t)P##i##1;            \
        const uint32_t e2 = (sel##i & 4u) ? (uint32_t)(P##i##2 >> 32)     \
                                          : (uint32_t)P##i##2;            \
        const uint32_t e3 = (sel##i & 8u) ? (uint32_t)(P##i##3 >> 32)     \
                                          : (uint32_t)P##i##3;            \
        float a0 = 0.f, a1 = 0.f;                                         \
        a0 = fmaf(w0, fmaf(wx0, bflo(e0), wx1 * bflo(S##i##0)), a0);      \
        a1 = fmaf(w0, fmaf(wx0, bfhi(e0), wx1 * bfhi(S##i##0)), a1);      \
        a0 = fmaf(w1, fmaf(wx0, bflo(e1), wx1 * bflo(S##i##1)), a0);      \
        a1 = fmaf(w1, fmaf(wx0, bfhi(e1), wx1 * bfhi(S##i##1)), a1);      \
        a0 = fmaf(w2, fmaf(wx0, bflo(e2), wx1 * bflo(S##i##2)), a0);      \
        a1 = fmaf(w2, fmaf(wx0, bfhi(e2), wx1 * bfhi(S##i##2)), a1);      \
        a0 = fmaf(w3, fmaf(wx0, bflo(e3), wx1 * bflo(S##i##3)), a0);      \
        a1 = fmaf(w3, fmaf(wx0, bfhi(e3), wx1 * bfhi(S##i##3)), a1);      \
        w[n0 + i * 256] = bf16_rtne_hi(a0) | (bf16_rtne_hi(a1) << 16);    \
    }

__global__ __launch_bounds__(256) void fine_kernel(
    const float* __restrict__ x,
    const uint32_t* __restrict__ packed,
    uint32_t* __restrict__ lvl_out)
{
    const int b = blockIdx.x;
    const int level = 7 + (b >> 11);       // level-at-a-time machine fill
    const int chunk = b & 2047;

    const float r = c_res[level];
    const uint32_t* __restrict__ tab = packed + (size_t)level * kTableSize;
    uint32_t* __restrict__ w = lvl_out + (size_t)level * kPoints;

    const int n0 = chunk * 1024 + threadIdx.x;

    FINE_DECL(0) FINE_DECL(1) FINE_DECL(2) FINE_DECL(3)

    // phase X: ALL compiler VMEM up front (so its waitcnt insertion
    // happens before the asm pipeline starts and can't drain it).
    const float px0 = fminf(fmaxf(x[3 * (n0 + 0 * 256) + 0], 0.f), 1.f);
    const float py0 = fminf(fmaxf(x[3 * (n0 + 0 * 256) + 1], 0.f), 1.f);
    const float pz0 = fminf(fmaxf(x[3 * (n0 + 0 * 256) + 2], 0.f), 1.f);
    const float px1 = fminf(fmaxf(x[3 * (n0 + 1 * 256) + 0], 0.f), 1.f);
    const float py1 = fminf(fmaxf(x[3 * (n0 + 1 * 256) + 1], 0.f), 1.f);
    const float pz1 = fminf(fmaxf(x[3 * (n0 + 1 * 256) + 2], 0.f), 1.f);
    const float px2 = fminf(fmaxf(x[3 * (n0 + 2 * 256) + 0], 0.f), 1.f);
    const float py2 = fminf(fmaxf(x[3 * (n0 + 2 * 256) + 1], 0.f), 1.f);
    const float pz2 = fminf(fmaxf(x[3 * (n0 + 2 * 256) + 2], 0.f), 1.f);
    const float px3 = fminf(fmaxf(x[3 * (n0 + 3 * 256) + 0], 0.f), 1.f);
    const float py3 = fminf(fmaxf(x[3 * (n0 + 3 * 256) + 1], 0.f), 1.f);
    const float pz3 = fminf(fmaxf(x[3 * (n0 + 3 * 256) + 2], 0.f), 1.f);
    __builtin_amdgcn_sched_barrier(0);

    // phase I: 32 asm gathers, back to back (VALU hash calc interleaved).
    FINE_ISSUE(0)
    FINE_ISSUE(1)
    FINE_ISSUE(2)
    FINE_ISSUE(3)

    // phase C: consume ladder with counted vmcnt (8 loads retire/step).
    asm volatile("s_waitcnt vmcnt(24)");
    __builtin_amdgcn_sched_barrier(0);
    FINE_CONSUME(0)
    asm volatile("s_waitcnt vmcnt(16)");
    __builtin_amdgcn_sched_barrier(0);
    FINE_CONSUME(1)
    asm volatile("s_waitcnt vmcnt(8)");
    __builtin_amdgcn_sched_barrier(0);
    FINE_CONSUME(2)
    asm volatile("s_waitcnt vmcnt(0)");
    __builtin_amdgcn_sched_barrier(0);
    FINE_CONSUME(3)
}

// ---------------- pass 2: level-major bf16 -> [N][32] f32 ----------------
__global__ __launch_bounds__(256) void untile_kernel(
    const uint32_t* __restrict__ lvl_out, float* __restrict__ out)
{
    const int n = blockIdx.x * 256 + threadIdx.x;
    float vals[2 * kLevels];
#pragma unroll
    for (int l = 0; l < kLevels; ++l) {
        const uint32_t u = lvl_out[(size_t)l * kPoints + n];
        vals[2 * l + 0] = bflo(u);
        vals[2 * l + 1] = bfhi(u);
    }
    float4* o4 = reinterpret_cast<float4*>(out + (size_t)n * (2 * kLevels));
#pragma unroll
    for (int kq = 0; kq < 8; ++kq) {
        o4[kq] = make_float4(vals[4 * kq + 0], vals[4 * kq + 1],
                             vals[4 * kq + 2], vals[4 * kq + 3]);
    }
}

// ---------------- fallbacks (round-0/round-2 proven paths) --------------
__device__ __forceinline__ void eval_level(
    float px, float py, float pz, float r,
    const uint32_t* __restrict__ tab, float& a0, float& a1)
{
    const float tx = px * r, ty = py * r, tz = pz * r;
    const float fx = floorf(tx), fy = floorf(ty), fz = floorf(tz);
    const int bx = (int)fx, by = (int)fy, bz = (int)fz;
    const float rx = tx - fx, ry = ty - fy, rz = tz - fz;

    const uint32_t hx0 = (uint32_t)bx;
    const uint32_t hx1 = (uint32_t)(bx + 1);
    const uint32_t hy0 = (uint32_t)by * 2654435761u;
    const uint32_t hy1 = (uint32_t)(by + 1) * 2654435761u;
    const uint32_t hz0 = (uint32_t)bz * 805459861u;
    const uint32_t hz1 = (uint32_t)(bz + 1) * 805459861u;

    const float wx1 = rx, wx0 = 1.0f - rx;
    const float wy1 = ry, wy0 = 1.0f - ry;
    const float wz1 = rz, wz0 = 1.0f - rz;

    a0 = 0.0f; a1 = 0.0f;
#pragma unroll
    for (int c = 0; c < 8; ++c) {
        const uint32_t h = (((c & 4) ? hx1 : hx0) ^
                            ((c & 2) ? hy1 : hy0) ^
                            ((c & 1) ? hz1 : hz0)) & kMask;
        const uint32_t e = tab[h];
        const float w = ((c & 4) ? wx1 : wx0) *
                        ((c & 2) ? wy1 : wy0) *
                        ((c & 1) ? wz1 : wz0);
        a0 = fmaf(w, bflo(e), a0);
        a1 = fmaf(w, bfhi(e), a1);
    }
}

__global__ __launch_bounds__(256) void direct_kernel(
    const float* __restrict__ x,
    const float* __restrict__ tables,
    float* __restrict__ out)
{
    const int n = blockIdx.x * 256 + threadIdx.x;
    float px = fminf(fmaxf(x[3 * n + 0], 0.0f), 1.0f);
    float py = fminf(fmaxf(x[3 * n + 1], 0.0f), 1.0f);
    float pz = fminf(fmaxf(x[3 * n + 2], 0.0f), 1.0f);

    const float res_tab[kLevels] = {
        16.f, 20.f, 25.f, 32.f, 40.f, 50.f, 64.f, 80.f,
        101.f, 128.f, 161.f, 203.f, 256.f, 322.f, 406.f, 512.f};

    float acc[2 * kLevels];
#pragma unroll
    for (int l = 0; l < kLevels; ++l) {
        const float r = res_tab[l];
        const float tx = px * r, ty = py * r, tz = pz * r;
        const float fx = floorf(tx), fy = floorf(ty), fz = floorf(tz);
        const int bx = (int)fx, by = (int)fy, bz = (int)fz;
        const float rx = tx - fx, ry = ty - fy, rz = tz - fz;
        const uint32_t hx0 = (uint32_t)bx;
        const uint32_t hx1 = (uint32_t)(bx + 1);
        const uint32_t hy0 = (uint32_t)by * 2654435761u;
        const uint32_t hy1 = (uint32_t)(by + 1) * 2654435761u;
        const uint32_t hz0 = (uint32_t)bz * 805459861u;
        const uint32_t hz1 = (uint32_t)(bz + 1) * 805459861u;
        const float wx1 = rx, wx0 = 1.0f - rx;
        const float wy1 = ry, wy0 = 1.0f - ry;
        const float wz1 = rz, wz0 = 1.0f - rz;
        const float2* __restrict__ tab =
            reinterpret_cast<const float2*>(tables) + (size_t)l * kTableSize;
        float a0 = 0.0f, a1 = 0.0f;
#pragma unroll
        for (int c = 0; c < 8; ++c) {
            const uint32_t h = (((c & 4) ? hx1 : hx0) ^
                                ((c & 2) ? hy1 : hy0) ^
                                ((c & 1) ? hz1 : hz0)) & kMask;
            const float2 e = tab[h];
            const float w = ((c & 4) ? wx1 : wx0) *
                            ((c & 2) ? wy1 : wy0) *
                            ((c & 1) ? wz1 : wz0);
            a0 = fmaf(w, e.x, a0);
            a1 = fmaf(w, e.y, a1);
        }
        acc[2 * l + 0] = a0;
        acc[2 * l + 1] = a1;
    }
    float4* o4 = reinterpret_cast<float4*>(out + (size_t)n * (2 * kLevels));
#pragma unroll
    for (int kq = 0; kq < 8; ++kq) {
        o4[kq] = make_float4(acc[4 * kq + 0], acc[4 * kq + 1],
                             acc[4 * kq + 2], acc[4 * kq + 3]);
    }
}

__global__ __launch_bounds__(256) void direct_packed_kernel(
    const float* __restrict__ x,
    const uint32_t* __restrict__ packed,
    float* __restrict__ out)
{
    const int n = blockIdx.x * 256 + threadIdx.x;
    float px = fminf(fmaxf(x[3 * n + 0], 0.0f), 1.0f);
    float py = fminf(fmaxf(x[3 * n + 1], 0.0f), 1.0f);
    float pz = fminf(fmaxf(x[3 * n + 2], 0.0f), 1.0f);

    const float res_tab[kLevels] = {
        16.f, 20.f, 25.f, 32.f, 40.f, 50.f, 64.f, 80.f,
        101.f, 128.f, 161.f, 203.f, 256.f, 322.f, 406.f, 512.f};

    float acc[2 * kLevels];
#pragma unroll
    for (int l = 0; l < kLevels; ++l) {
        float a0, a1;
        eval_level(px, py, pz, res_tab[l],
                   packed + (size_t)l * kTableSize, a0, a1);
        acc[2 * l + 0] = a0;
        acc[2 * l + 1] = a1;
    }
    float4* o4 = reinterpret_cast<float4*>(out + (size_t)n * (2 * kLevels));
#pragma unroll
    for (int kq = 0; kq < 8; ++kq) {
        o4[kq] = make_float4(acc[4 * kq + 0], acc[4 * kq + 1],
                             acc[4 * kq + 2], acc[4 * kq + 3]);
    }
}

extern "C" void kernel_launch(void* const* d_in, const int* in_sizes, int n_in,
                              void* d_out, int out_size, void* d_ws, size_t ws_size,
                              hipStream_t stream) {
    const float* x = (const float*)d_in[0];       // [2^21, 3] f32
    const float* tables = (const float*)d_in[1];  // [16, 2^19, 2] f32
    float* out = (float*)d_out;                   // [2^21, 32] f32

    if (ws_size >= kPackedBytes + kLvlOutBytes) {
        char* ws = (char*)d_ws;
        uint32_t* packed = (uint32_t*)ws;
        uint32_t* lvl_out = (uint32_t*)(ws + kPackedBytes);
        uint32_t* dense012 = (uint32_t*)ws;  // overlays packed[0..2] (unused)

        hipLaunchKernelGGL(pack_tables_kernel,
                           dim3((kLevels * kTableSize / 2) / 256), dim3(256),
                           0, stream, tables, packed);
        // builds overwrite the packed[0..2] region only; readers of
        // packed[3..6] (build_x4) and packed[7..15] (fine) are untouched.
        hipLaunchKernelGGL(build_dense012_kernel,
                           dim3((kNDense + 255) / 256), dim3(256),
                           0, stream, tables, dense012);
        hipLaunchKernelGGL(build_x4_kernel,
                           dim3((kGTot + 255) / 256), dim3(256),
                           0, stream, packed, ws);
        // pass A: levels 0-2 (LDS), 1024 blocks x 512 thr x 4 pts
        hipLaunchKernelGGL(coarse_kernel, dim3(kPoints / 2048), dim3(512),
                           0, stream, x, dense012, lvl_out);
        // pass B: levels 3-6 (dense-x4), 4 x 2048 blocks
        hipLaunchKernelGGL(mid_kernel, dim3(4 * 2048), dim3(256),
                           0, stream, x, (const char*)ws, lvl_out);
        // pass C: levels 7-15 (hashed, asm-pipelined), 9 x 2048 blocks
        hipLaunchKernelGGL(fine_kernel, dim3(9 * 2048), dim3(256),
                           0, stream, x, packed, lvl_out);
        // pass 2
        hipLaunchKernelGGL(untile_kernel, dim3(kPoints / 256), dim3(256),
                           0, stream, lvl_out, out);
    } else if (ws_size >= kPackedBytes) {
        uint32_t* packed = (uint32_t*)d_ws;
        hipLaunchKernelGGL(pack_tables_kernel,
                           dim3((kLevels * kTableSize / 2) / 256), dim3(256),
                           0, stream, tables, packed);
        hipLaunchKernelGGL(direct_packed_kernel, dim3(kPoints / 256), dim3(256),
                           0, stream, x, packed, out);
    } else {
        hipLaunchKernelGGL(direct_kernel, dim3(kPoints / 256), dim3(256),
                           0, stream, x, tables, out);
    }
}

// Round 11
// 562.127 us; speedup vs baseline: 1.1042x; 1.1042x over previous
//
#include <hip/hip_runtime.h>
#include <stdint.h>

// HashEmbedder (Instant-NGP multires hash grid), 16 levels, F=2, T=2^19,
// N = 2^21 points.
//
// Round-11: fine reverted to round-9 (340us; r10 asm-MLP proved the gather
// loop is THROUGHPUT-bound at ~0.5 lines/cyc/CU, not latency-bound).
// New: mid levels 3-6 via per-VOXEL 8-corner cluster tables (32B/voxel,
// 32B-aligned -> 2x dwordx4 requests, ONE cache line per point per level,
// vs x4's 4 requests / 4 lines). V3-5 live in the freed packed[0..5]
// region (pack now covers levels 7-15 only); V6 (8.8MB) is staged in the
// lvl_out[7] slice and consumed by mid BEFORE fine overwrites it (strict
// in-stream ordering).
//
//   pass 0 : pack f32 tables -> bf16x2 (levels 7-15 only).
//   pass 0b: dense de-hashed tables levels 0-2 (124 KB); voxel-cluster
//            tables V3..V6 (hash 8 corners per voxel, 32B each).
//   pass A : levels 0-2 via LDS-staged dense tables.
//   pass B : levels 3-6 via voxel-cluster tables (1 line/pt/level).
//   pass C : levels 7-15 hashed, level-at-a-time, paired (round-9 form).
//   pass 2 : transpose level-major bf16x2 -> [N][32] f32.

constexpr int kLevels = 16;
constexpr int kPoints = 1 << 21;
constexpr uint32_t kTableSize = 1u << 19;
constexpr uint32_t kMask = kTableSize - 1u;
constexpr size_t kPackedBytes = (size_t)kLevels * kTableSize * 4;  // 32 MB
constexpr size_t kLvlOutBytes = (size_t)kLevels * kPoints * 4;     // 128 MB

typedef float f32x4 __attribute__((ext_vector_type(4)));
typedef uint32_t u32x4 __attribute__((ext_vector_type(4)));

// dense coarse (levels 0-2): entry counts and bases (uint32 units)
constexpr int kS0 = 17, kS1 = 21, kS2 = 26;            // res+1
constexpr int kN0 = kS0 * kS0 * kS0;                   // 4913
constexpr int kN1 = kS1 * kS1 * kS1;                   // 9261
constexpr int kN2 = kS2 * kS2 * kS2;                   // 17576
constexpr int kB1 = kN0, kB2 = kN0 + kN1;              // 4913, 14174
constexpr int kNDense = kN0 + kN1 + kN2;               // 31750

// voxel-cluster tables (levels 3-6): (res+1)^3 voxels x 32B
constexpr int kV3n = 33 * 33 * 33;   // 35937
constexpr int kV4n = 41 * 41 * 41;   // 68921
constexpr int kV5n = 51 * 51 * 51;   // 132651
constexpr int kV6n = 65 * 65 * 65;   // 274625
constexpr int kVTot = kV3n + kV4n + kV5n + kV6n;       // 512134
// byte offsets inside ws (V3-5 in freed packed[0..5] region, 12 MB)
constexpr size_t kV3Base = 131072;                         // after dense012
constexpr size_t kV4Base = kV3Base + (size_t)kV3n * 32;    // 1281056
constexpr size_t kV5Base = kV4Base + (size_t)kV4n * 32;    // 3486528
// end V5 = 7731360 < 12 MB (packed levels 0-5, now unused). OK.
// V6 lives in lvl_out slice 7 (+ spills 0.4MB into slice 8): read by mid,
// clobbered only later by fine. offset relative to ws:
constexpr size_t kV6Base = kPackedBytes + (size_t)7 * kPoints * 4;

// floor(16 * b^i), b = exp(ln(32)/15) in f64 (boundary levels round up).
__constant__ float c_res[kLevels] = {
    16.f, 20.f, 25.f, 32.f, 40.f, 50.f, 64.f, 80.f,
    101.f, 128.f, 161.f, 203.f, 256.f, 322.f, 406.f, 512.f};

__device__ __forceinline__ uint32_t bf16_rtne_hi(float f) {
    uint32_t u = __float_as_uint(f);
    return (u + 0x7FFFu + ((u >> 16) & 1u)) >> 16;
}
__device__ __forceinline__ float bflo(uint32_t e) {
    return __uint_as_float(e << 16);
}
__device__ __forceinline__ float bfhi(uint32_t e) {
    return __uint_as_float(e & 0xFFFF0000u);
}

// ------- pass 0: pack tables to bf16x2 (levels 7-15 only, main path) ----
__global__ __launch_bounds__(256) void pack_tables_kernel(
    const float* __restrict__ tables, uint32_t* __restrict__ packed, int base)
{
    const int i = base + blockIdx.x * 256 + threadIdx.x;  // 2 entries/thread
    const f32x4 v = reinterpret_cast<const f32x4*>(tables)[i];
    uint2 o;
    o.x = bf16_rtne_hi(v.x) | (bf16_rtne_hi(v.y) << 16);
    o.y = bf16_rtne_hi(v.z) | (bf16_rtne_hi(v.w) << 16);
    reinterpret_cast<uint2*>(packed)[i] = o;
}

// ---------------- pass 0b-1: dense de-hashed tables, levels 0-2 --------
template <int S, int LVL>
__device__ __forceinline__ void build_dense_one(
    int r, const float* __restrict__ tables, uint32_t* __restrict__ dst)
{
    const int bz = r % S;
    const int t = r / S;
    const int by = t % S;
    const int bx = t / S;
    const uint32_t h = ((uint32_t)bx ^ ((uint32_t)by * 2654435761u) ^
                        ((uint32_t)bz * 805459861u)) & kMask;
    const float* src = tables + (((size_t)LVL << 19) + h) * 2;
    dst[r] = bf16_rtne_hi(src[0]) | (bf16_rtne_hi(src[1]) << 16);
}

__global__ __launch_bounds__(256) void build_dense012_kernel(
    const float* __restrict__ tables, uint32_t* __restrict__ dense)
{
    const int idx = blockIdx.x * 256 + threadIdx.x;
    if (idx >= kNDense) return;
    if (idx < kB1)      build_dense_one<kS0, 0>(idx,       tables, dense);
    else if (idx < kB2) build_dense_one<kS1, 1>(idx - kB1, tables, dense + kB1);
    else                build_dense_one<kS2, 2>(idx - kB2, tables, dense + kB2);
}

// --------- pass 0b-2: voxel-cluster tables, levels 3-6 ------------------
// V[(bx*S+by)*S+bz] = 8 corner entries (bf16x2 each), corner index
// c = (dx<<2)|(dy<<1)|dz (matches OFFSETS bit mapping), 32B per voxel.
template <int S, int LVL>
__device__ __forceinline__ void build_vox_one(
    int v, const float* __restrict__ tables, u32x4* __restrict__ dst)
{
    const int bz = v % S;
    const int t = v / S;
    const int by = t % S;
    const int bx = t / S;
    const float* tab = tables + (((size_t)LVL << 19) * 2);
    uint32_t e[8];
#pragma unroll
    for (int c = 0; c < 8; ++c) {
        const uint32_t xx = (uint32_t)(bx + ((c >> 2) & 1));
        const uint32_t yy = (uint32_t)(by + ((c >> 1) & 1));
        const uint32_t zz = (uint32_t)(bz + (c & 1));
        const uint32_t h = (xx ^ (yy * 2654435761u) ^ (zz * 805459861u)) & kMask;
        const float* src = tab + (size_t)h * 2;
        e[c] = bf16_rtne_hi(src[0]) | (bf16_rtne_hi(src[1]) << 16);
    }
    u32x4 q0, q1;
    q0.x = e[0]; q0.y = e[1]; q0.z = e[2]; q0.w = e[3];
    q1.x = e[4]; q1.y = e[5]; q1.z = e[6]; q1.w = e[7];
    dst[2 * v + 0] = q0;
    dst[2 * v + 1] = q1;
}

__global__ __launch_bounds__(256) void build_vox_kernel(
    const float* __restrict__ tables, char* __restrict__ ws)
{
    const int v = blockIdx.x * 256 + threadIdx.x;
    if (v >= kVTot) return;
    if (v < kV3n)
        build_vox_one<33, 3>(v, tables, (u32x4*)(ws + kV3Base));
    else if (v < kV3n + kV4n)
        build_vox_one<41, 4>(v - kV3n, tables, (u32x4*)(ws + kV4Base));
    else if (v < kV3n + kV4n + kV5n)
        build_vox_one<51, 5>(v - kV3n - kV4n, tables, (u32x4*)(ws + kV5Base));
    else
        build_vox_one<65, 6>(v - kV3n - kV4n - kV5n, tables,
                             (u32x4*)(ws + kV6Base));
}

// ---------------- pass A: levels 0-2 via LDS dense tables ----------------
template <int S, int BASE, int LVL>
__device__ __forceinline__ void eval_coarse(
    const uint32_t* __restrict__ lds, float px, float py, float pz, float r,
    uint32_t* __restrict__ lvl_out, int n)
{
    const float tx = px * r, ty = py * r, tz = pz * r;
    const float fx = floorf(tx), fy = floorf(ty), fz = floorf(tz);
    const int bx = (int)fx, by = (int)fy, bz = (int)fz;
    const float rx = tx - fx, ry = ty - fy, rz = tz - fz;
    const int c = BASE + (bx * S + by) * S + bz;
    const uint32_t e000 = lds[c],             e001 = lds[c + 1];
    const uint32_t e010 = lds[c + S],         e011 = lds[c + S + 1];
    const uint32_t e100 = lds[c + S * S],     e101 = lds[c + S * S + 1];
    const uint32_t e110 = lds[c + S * S + S], e111 = lds[c + S * S + S + 1];
    const float wx1 = rx, wx0 = 1.f - rx;
    const float wy1 = ry, wy0 = 1.f - ry;
    const float wz1 = rz, wz0 = 1.f - rz;
    float a0 = 0.f, a1 = 0.f;
    a0 = fmaf(wx0 * wy0 * wz0, bflo(e000), a0);
    a1 = fmaf(wx0 * wy0 * wz0, bfhi(e000), a1);
    a0 = fmaf(wx0 * wy0 * wz1, bflo(e001), a0);
    a1 = fmaf(wx0 * wy0 * wz1, bfhi(e001), a1);
    a0 = fmaf(wx0 * wy1 * wz0, bflo(e010), a0);
    a1 = fmaf(wx0 * wy1 * wz0, bfhi(e010), a1);
    a0 = fmaf(wx0 * wy1 * wz1, bflo(e011), a0);
    a1 = fmaf(wx0 * wy1 * wz1, bfhi(e011), a1);
    a0 = fmaf(wx1 * wy0 * wz0, bflo(e100), a0);
    a1 = fmaf(wx1 * wy0 * wz0, bfhi(e100), a1);
    a0 = fmaf(wx1 * wy0 * wz1, bflo(e101), a0);
    a1 = fmaf(wx1 * wy0 * wz1, bfhi(e101), a1);
    a0 = fmaf(wx1 * wy1 * wz0, bflo(e110), a0);
    a1 = fmaf(wx1 * wy1 * wz0, bfhi(e110), a1);
    a0 = fmaf(wx1 * wy1 * wz1, bflo(e111), a0);
    a1 = fmaf(wx1 * wy1 * wz1, bfhi(e111), a1);
    lvl_out[(size_t)LVL * kPoints + n] =
        bf16_rtne_hi(a0) | (bf16_rtne_hi(a1) << 16);
}

__global__ __launch_bounds__(512) void coarse_kernel(
    const float* __restrict__ x, const uint32_t* __restrict__ dense,
    uint32_t* __restrict__ lvl_out)
{
    __shared__ uint32_t s_tab[kNDense];  // 127000 B
    for (int i = threadIdx.x; i < kNDense; i += 512) s_tab[i] = dense[i];
    __syncthreads();

    const int n0 = blockIdx.x * 2048 + threadIdx.x;
#pragma unroll
    for (int k = 0; k < 4; ++k) {
        const int n = n0 + k * 512;
        const float px = fminf(fmaxf(x[3 * n + 0], 0.0f), 1.0f);
        const float py = fminf(fmaxf(x[3 * n + 1], 0.0f), 1.0f);
        const float pz = fminf(fmaxf(x[3 * n + 2], 0.0f), 1.0f);
        eval_coarse<kS0, 0,   0>(s_tab, px, py, pz, 16.f, lvl_out, n);
        eval_coarse<kS1, kB1, 1>(s_tab, px, py, pz, 20.f, lvl_out, n);
        eval_coarse<kS2, kB2, 2>(s_tab, px, py, pz, 25.f, lvl_out, n);
    }
}

// -------- pass B: levels 3-6 via voxel-cluster tables (1 line/pt) -------
template <int R, int LVL>
__device__ __forceinline__ void eval_vox(
    const u32x4* __restrict__ V, float px, float py, float pz,
    uint32_t* __restrict__ lvl_out, int n)
{
    const float r = (float)R;
    const float tx = px * r, ty = py * r, tz = pz * r;
    const float fx = floorf(tx), fy = floorf(ty), fz = floorf(tz);
    const int bx = (int)fx, by = (int)fy, bz = (int)fz;
    const float rx = tx - fx, ry = ty - fy, rz = tz - fz;
    constexpr int S = R + 1;
    const int idx = (bx * S + by) * S + bz;
    const u32x4 q0 = V[2 * idx + 0];   // corners 0-3 (x = bx side)
    const u32x4 q1 = V[2 * idx + 1];   // corners 4-7 (x = bx+1 side)
    const float wx1 = rx, wx0 = 1.f - rx;
    const float wy1 = ry, wy0 = 1.f - ry;
    const float wz1 = rz, wz0 = 1.f - rz;
    float a0 = 0.f, a1 = 0.f;
    a0 = fmaf(wx0 * wy0 * wz0, bflo(q0.x), a0);
    a1 = fmaf(wx0 * wy0 * wz0, bfhi(q0.x), a1);
    a0 = fmaf(wx0 * wy0 * wz1, bflo(q0.y), a0);
    a1 = fmaf(wx0 * wy0 * wz1, bfhi(q0.y), a1);
    a0 = fmaf(wx0 * wy1 * wz0, bflo(q0.z), a0);
    a1 = fmaf(wx0 * wy1 * wz0, bfhi(q0.z), a1);
    a0 = fmaf(wx0 * wy1 * wz1, bflo(q0.w), a0);
    a1 = fmaf(wx0 * wy1 * wz1, bfhi(q0.w), a1);
    a0 = fmaf(wx1 * wy0 * wz0, bflo(q1.x), a0);
    a1 = fmaf(wx1 * wy0 * wz0, bfhi(q1.x), a1);
    a0 = fmaf(wx1 * wy0 * wz1, bflo(q1.y), a0);
    a1 = fmaf(wx1 * wy0 * wz1, bfhi(q1.y), a1);
    a0 = fmaf(wx1 * wy1 * wz0, bflo(q1.z), a0);
    a1 = fmaf(wx1 * wy1 * wz0, bfhi(q1.z), a1);
    a0 = fmaf(wx1 * wy1 * wz1, bflo(q1.w), a0);
    a1 = fmaf(wx1 * wy1 * wz1, bfhi(q1.w), a1);
    lvl_out[(size_t)LVL * kPoints + n] =
        bf16_rtne_hi(a0) | (bf16_rtne_hi(a1) << 16);
}

__global__ __launch_bounds__(256) void mid_kernel(
    const float* __restrict__ x, const char* __restrict__ ws,
    uint32_t* __restrict__ lvl_out)
{
    const int b = blockIdx.x;
    const int sub = b >> 11;                 // 0..3 -> level 3..6
    const int chunk = b & 2047;
    const int n0 = chunk * 1024 + threadIdx.x;
#pragma unroll
    for (int k = 0; k < 4; ++k) {
        const int n = n0 + k * 256;
        const float px = fminf(fmaxf(x[3 * n + 0], 0.0f), 1.0f);
        const float py = fminf(fmaxf(x[3 * n + 1], 0.0f), 1.0f);
        const float pz = fminf(fmaxf(x[3 * n + 2], 0.0f), 1.0f);
        if (sub == 0)
            eval_vox<32, 3>((const u32x4*)(ws + kV3Base), px, py, pz, lvl_out, n);
        else if (sub == 1)
            eval_vox<40, 4>((const u32x4*)(ws + kV4Base), px, py, pz, lvl_out, n);
        else if (sub == 2)
            eval_vox<50, 5>((const u32x4*)(ws + kV5Base), px, py, pz, lvl_out, n);
        else
            eval_vox<64, 6>((const u32x4*)(ws + kV6Base), px, py, pz, lvl_out, n);
    }
}

// ------- pass C: levels 7-15 hashed, pinned 2-deep pipeline (round 9) ---
struct PtSt {
    float rx, ry, rz;
    uint32_t sel;              // bit j = half-selector for corner pair j
    uint2 p0, p1, p2, p3;      // corner-pair entries (elo/ehi encoded)
};

__device__ __forceinline__ void issue_pt(
    PtSt& st, const float* __restrict__ x, int n, float r,
    const uint32_t* __restrict__ tab)
{
    const float px = fminf(fmaxf(x[3 * n + 0], 0.f), 1.f);
    const float py = fminf(fmaxf(x[3 * n + 1], 0.f), 1.f);
    const float pz = fminf(fmaxf(x[3 * n + 2], 0.f), 1.f);
    const float tx = px * r, ty = py * r, tz = pz * r;
    const float fx = floorf(tx), fy = floorf(ty), fz = floorf(tz);
    const int bx = (int)fx, by = (int)fy, bz = (int)fz;
    st.rx = tx - fx;  st.ry = ty - fy;  st.rz = tz - fz;
    const uint32_t hy0 = (uint32_t)by * 2654435761u;
    const uint32_t hy1 = (uint32_t)(by + 1) * 2654435761u;
    const uint32_t hz0 = (uint32_t)bz * 805459861u;
    const uint32_t hz1 = (uint32_t)(bz + 1) * 805459861u;
    const uint32_t bxu = (uint32_t)bx, bx1 = bxu + 1u;
    const uint32_t m0 = hy0 ^ hz0, m1 = hy0 ^ hz1;
    const uint32_t m2 = hy1 ^ hz0, m3 = hy1 ^ hz1;
    if ((bx & 1) == 0) {
        const uint32_t h0 = (bxu ^ m0) & kMask;
        const uint32_t h1 = (bxu ^ m1) & kMask;
        const uint32_t h2 = (bxu ^ m2) & kMask;
        const uint32_t h3 = (bxu ^ m3) & kMask;
        st.sel = (h0 & 1u) | ((h1 & 1u) << 1) |
                 ((h2 & 1u) << 2) | ((h3 & 1u) << 3);
        st.p0 = *reinterpret_cast<const uint2*>(tab + (h0 & ~1u));
        st.p1 = *reinterpret_cast<const uint2*>(tab + (h1 & ~1u));
        st.p2 = *reinterpret_cast<const uint2*>(tab + (h2 & ~1u));
        st.p3 = *reinterpret_cast<const uint2*>(tab + (h3 & ~1u));
    } else {
        st.sel = 0u;
        st.p0.x = tab[(bxu ^ m0) & kMask];  st.p0.y = tab[(bx1 ^ m0) & kMask];
        st.p1.x = tab[(bxu ^ m1) & kMask];  st.p1.y = tab[(bx1 ^ m1) & kMask];
        st.p2.x = tab[(bxu ^ m2) & kMask];  st.p2.y = tab[(bx1 ^ m2) & kMask];
        st.p3.x = tab[(bxu ^ m3) & kMask];  st.p3.y = tab[(bx1 ^ m3) & kMask];
    }
}

__device__ __forceinline__ void consume_pt(
    const PtSt& st, uint32_t* __restrict__ w, int n)
{
    const float wx1 = st.rx, wx0 = 1.f - st.rx;
    const float wy1 = st.ry, wy0 = 1.f - st.ry;
    const float wz1 = st.rz, wz0 = 1.f - st.rz;
    const float w0 = wy0 * wz0, w1 = wy0 * wz1;
    const float w2 = wy1 * wz0, w3 = wy1 * wz1;
    const uint32_t e0 = (st.sel & 1u) ? st.p0.y : st.p0.x;
    const uint32_t f0 = (st.sel & 1u) ? st.p0.x : st.p0.y;
    const uint32_t e1 = (st.sel & 2u) ? st.p1.y : st.p1.x;
    const uint32_t f1 = (st.sel & 2u) ? st.p1.x : st.p1.y;
    const uint32_t e2 = (st.sel & 4u) ? st.p2.y : st.p2.x;
    const uint32_t f2 = (st.sel & 4u) ? st.p2.x : st.p2.y;
    const uint32_t e3 = (st.sel & 8u) ? st.p3.y : st.p3.x;
    const uint32_t f3 = (st.sel & 8u) ? st.p3.x : st.p3.y;
    float a0 = 0.f, a1 = 0.f;
    a0 = fmaf(w0, fmaf(wx0, bflo(e0), wx1 * bflo(f0)), a0);
    a1 = fmaf(w0, fmaf(wx0, bfhi(e0), wx1 * bfhi(f0)), a1);
    a0 = fmaf(w1, fmaf(wx0, bflo(e1), wx1 * bflo(f1)), a0);
    a1 = fmaf(w1, fmaf(wx0, bfhi(e1), wx1 * bfhi(f1)), a1);
    a0 = fmaf(w2, fmaf(wx0, bflo(e2), wx1 * bflo(f2)), a0);
    a1 = fmaf(w2, fmaf(wx0, bfhi(e2), wx1 * bfhi(f2)), a1);
    a0 = fmaf(w3, fmaf(wx0, bflo(e3), wx1 * bflo(f3)), a0);
    a1 = fmaf(w3, fmaf(wx0, bfhi(e3), wx1 * bfhi(f3)), a1);
    w[n] = bf16_rtne_hi(a0) | (bf16_rtne_hi(a1) << 16);
}

__global__ __launch_bounds__(256) void fine_kernel(
    const float* __restrict__ x,
    const uint32_t* __restrict__ packed,
    uint32_t* __restrict__ lvl_out)
{
    const int b = blockIdx.x;
    const int level = 7 + (b >> 11);       // level-at-a-time machine fill
    const int chunk = b & 2047;

    const float r = c_res[level];
    const uint32_t* __restrict__ tab = packed + (size_t)level * kTableSize;
    uint32_t* __restrict__ w = lvl_out + (size_t)level * kPoints;

    const int n0 = chunk * 1024 + threadIdx.x;

    PtSt A, B;
    issue_pt(A, x, n0 + 0 * 256, r, tab);
    issue_pt(B, x, n0 + 1 * 256, r, tab);
    __builtin_amdgcn_sched_barrier(0);
    consume_pt(A, w, n0 + 0 * 256);
    __builtin_amdgcn_sched_barrier(0);
    issue_pt(A, x, n0 + 2 * 256, r, tab);
    __builtin_amdgcn_sched_barrier(0);
    consume_pt(B, w, n0 + 1 * 256);
    __builtin_amdgcn_sched_barrier(0);
    issue_pt(B, x, n0 + 3 * 256, r, tab);
    __builtin_amdgcn_sched_barrier(0);
    consume_pt(A, w, n0 + 2 * 256);
    __builtin_amdgcn_sched_barrier(0);
    consume_pt(B, w, n0 + 3 * 256);
}

// ---------------- pass 2: level-major bf16 -> [N][32] f32 ----------------
__global__ __launch_bounds__(256) void untile_kernel(
    const uint32_t* __restrict__ lvl_out, float* __restrict__ out)
{
    const int n = blockIdx.x * 256 + threadIdx.x;
    float vals[2 * kLevels];
#pragma unroll
    for (int l = 0; l < kLevels; ++l) {
        const uint32_t u = lvl_out[(size_t)l * kPoints + n];
        vals[2 * l + 0] = bflo(u);
        vals[2 * l + 1] = bfhi(u);
    }
    float4* o4 = reinterpret_cast<float4*>(out + (size_t)n * (2 * kLevels));
#pragma unroll
    for (int kq = 0; kq < 8; ++kq) {
        o4[kq] = make_float4(vals[4 * kq + 0], vals[4 * kq + 1],
                             vals[4 * kq + 2], vals[4 * kq + 3]);
    }
}

// ---------------- fallbacks (round-0/round-2 proven paths) --------------
__device__ __forceinline__ void eval_level(
    float px, float py, float pz, float r,
    const uint32_t* __restrict__ tab, float& a0, float& a1)
{
    const float tx = px * r, ty = py * r, tz = pz * r;
    const float fx = floorf(tx), fy = floorf(ty), fz = floorf(tz);
    const int bx = (int)fx, by = (int)fy, bz = (int)fz;
    const float rx = tx - fx, ry = ty - fy, rz = tz - fz;

    const uint32_t hx0 = (uint32_t)bx;
    const uint32_t hx1 = (uint32_t)(bx + 1);
    const uint32_t hy0 = (uint32_t)by * 2654435761u;
    const uint32_t hy1 = (uint32_t)(by + 1) * 2654435761u;
    const uint32_t hz0 = (uint32_t)bz * 805459861u;
    const uint32_t hz1 = (uint32_t)(bz + 1) * 805459861u;

    const float wx1 = rx, wx0 = 1.0f - rx;
    const float wy1 = ry, wy0 = 1.0f - ry;
    const float wz1 = rz, wz0 = 1.0f - rz;

    a0 = 0.0f; a1 = 0.0f;
#pragma unroll
    for (int c = 0; c < 8; ++c) {
        const uint32_t h = (((c & 4) ? hx1 : hx0) ^
                            ((c & 2) ? hy1 : hy0) ^
                            ((c & 1) ? hz1 : hz0)) & kMask;
        const uint32_t e = tab[h];
        const float w = ((c & 4) ? wx1 : wx0) *
                        ((c & 2) ? wy1 : wy0) *
                        ((c & 1) ? wz1 : wz0);
        a0 = fmaf(w, bflo(e), a0);
        a1 = fmaf(w, bfhi(e), a1);
    }
}

__global__ __launch_bounds__(256) void direct_kernel(
    const float* __restrict__ x,
    const float* __restrict__ tables,
    float* __restrict__ out)
{
    const int n = blockIdx.x * 256 + threadIdx.x;
    float px = fminf(fmaxf(x[3 * n + 0], 0.0f), 1.0f);
    float py = fminf(fmaxf(x[3 * n + 1], 0.0f), 1.0f);
    float pz = fminf(fmaxf(x[3 * n + 2], 0.0f), 1.0f);

    const float res_tab[kLevels] = {
        16.f, 20.f, 25.f, 32.f, 40.f, 50.f, 64.f, 80.f,
        101.f, 128.f, 161.f, 203.f, 256.f, 322.f, 406.f, 512.f};

    float acc[2 * kLevels];
#pragma unroll
    for (int l = 0; l < kLevels; ++l) {
        const float r = res_tab[l];
        const float tx = px * r, ty = py * r, tz = pz * r;
        const float fx = floorf(tx), fy = floorf(ty), fz = floorf(tz);
        const int bx = (int)fx, by = (int)fy, bz = (int)fz;
        const float rx = tx - fx, ry = ty - fy, rz = tz - fz;
        const uint32_t hx0 = (uint32_t)bx;
        const uint32_t hx1 = (uint32_t)(bx + 1);
        const uint32_t hy0 = (uint32_t)by * 2654435761u;
        const uint32_t hy1 = (uint32_t)(by + 1) * 2654435761u;
        const uint32_t hz0 = (uint32_t)bz * 805459861u;
        const uint32_t hz1 = (uint32_t)(bz + 1) * 805459861u;
        const float wx1 = rx, wx0 = 1.0f - rx;
        const float wy1 = ry, wy0 = 1.0f - ry;
        const float wz1 = rz, wz0 = 1.0f - rz;
        const float2* __restrict__ tab =
            reinterpret_cast<const float2*>(tables) + (size_t)l * kTableSize;
        float a0 = 0.0f, a1 = 0.0f;
#pragma unroll
        for (int c = 0; c < 8; ++c) {
            const uint32_t h = (((c & 4) ? hx1 : hx0) ^
                                ((c & 2) ? hy1 : hy0) ^
                                ((c & 1) ? hz1 : hz0)) & kMask;
            const float2 e = tab[h];
            const float w = ((c & 4) ? wx1 : wx0) *
                            ((c & 2) ? wy1 : wy0) *
                            ((c & 1) ? wz1 : wz0);
            a0 = fmaf(w, e.x, a0);
            a1 = fmaf(w, e.y, a1);
        }
        acc[2 * l + 0] = a0;
        acc[2 * l + 1] = a1;
    }
    float4* o4 = reinterpret_cast<float4*>(out + (size_t)n * (2 * kLevels));
#pragma unroll
    for (int kq = 0; kq < 8; ++kq) {
        o4[kq] = make_float4(acc[4 * kq + 0], acc[4 * kq + 1],
                             acc[4 * kq + 2], acc[4 * kq + 3]);
    }
}

__global__ __launch_bounds__(256) void direct_packed_kernel(
    const float* __restrict__ x,
    const uint32_t* __restrict__ packed,
    float* __restrict__ out)
{
    const int n = blockIdx.x * 256 + threadIdx.x;
    float px = fminf(fmaxf(x[3 * n + 0], 0.0f), 1.0f);
    float py = fminf(fmaxf(x[3 * n + 1], 0.0f), 1.0f);
    float pz = fminf(fmaxf(x[3 * n + 2], 0.0f), 1.0f);

    const float res_tab[kLevels] = {
        16.f, 20.f, 25.f, 32.f, 40.f, 50.f, 64.f, 80.f,
        101.f, 128.f, 161.f, 203.f, 256.f, 322.f, 406.f, 512.f};

    float acc[2 * kLevels];
#pragma unroll
    for (int l = 0; l < kLevels; ++l) {
        float a0, a1;
        eval_level(px, py, pz, res_tab[l],
                   packed + (size_t)l * kTableSize, a0, a1);
        acc[2 * l + 0] = a0;
        acc[2 * l + 1] = a1;
    }
    float4* o4 = reinterpret_cast<float4*>(out + (size_t)n * (2 * kLevels));
#pragma unroll
    for (int kq = 0; kq < 8; ++kq) {
        o4[kq] = make_float4(acc[4 * kq + 0], acc[4 * kq + 1],
                             acc[4 * kq + 2], acc[4 * kq + 3]);
    }
}

extern "C" void kernel_launch(void* const* d_in, const int* in_sizes, int n_in,
                              void* d_out, int out_size, void* d_ws, size_t ws_size,
                              hipStream_t stream) {
    const float* x = (const float*)d_in[0];       // [2^21, 3] f32
    const float* tables = (const float*)d_in[1];  // [16, 2^19, 2] f32
    float* out = (float*)d_out;                   // [2^21, 32] f32

    if (ws_size >= kPackedBytes + kLvlOutBytes) {
        char* ws = (char*)d_ws;
        uint32_t* packed = (uint32_t*)ws;
        uint32_t* lvl_out = (uint32_t*)(ws + kPackedBytes);
        uint32_t* dense012 = (uint32_t*)ws;  // overlays packed[0] (unused)

        // pack only levels 7-15 (fine path); levels 0-6 use dense/vox
        // tables built directly from the f32 input.
        hipLaunchKernelGGL(pack_tables_kernel,
                           dim3((9 << 19) / 2 / 256), dim3(256),
                           0, stream, tables, packed, (7 << 19) / 2);
        hipLaunchKernelGGL(build_dense012_kernel,
                           dim3((kNDense + 255) / 256), dim3(256),
                           0, stream, tables, dense012);
        // V3-5 in freed packed[0..5]; V6 in lvl_out slice 7 (read by mid
        // BEFORE fine overwrites it -- strict in-stream kernel order).
        hipLaunchKernelGGL(build_vox_kernel,
                           dim3((kVTot + 255) / 256), dim3(256),
                           0, stream, tables, ws);
        // pass A: levels 0-2 (LDS), 1024 blocks x 512 thr x 4 pts
        hipLaunchKernelGGL(coarse_kernel, dim3(kPoints / 2048), dim3(512),
                           0, stream, x, dense012, lvl_out);
        // pass B: levels 3-6 (voxel clusters), 4 x 2048 blocks
        hipLaunchKernelGGL(mid_kernel, dim3(4 * 2048), dim3(256),
                           0, stream, x, (const char*)ws, lvl_out);
        // pass C: levels 7-15 (hashed, pinned 2-deep pipe), 9 x 2048 blocks
        hipLaunchKernelGGL(fine_kernel, dim3(9 * 2048), dim3(256),
                           0, stream, x, packed, lvl_out);
        // pass 2
        hipLaunchKernelGGL(untile_kernel, dim3(kPoints / 256), dim3(256),
                           0, stream, lvl_out, out);
    } else if (ws_size >= kPackedBytes) {
        uint32_t* packed = (uint32_t*)d_ws;
        hipLaunchKernelGGL(pack_tables_kernel,
                           dim3((kLevels * kTableSize / 2) / 256), dim3(256),
                           0, stream, tables, packed, 0);
        hipLaunchKernelGGL(direct_packed_kernel, dim3(kPoints / 256), dim3(256),
                           0, stream, x, packed, out);
    } else {
        hipLaunchKernelGGL(direct_kernel, dim3(kPoints / 256), dim3(256),
                           0, stream, x, tables, out);
    }
}

// Round 12
// 557.106 us; speedup vs baseline: 1.1142x; 1.0090x over previous
//
#include <hip/hip_runtime.h>
#include <stdint.h>

// HashEmbedder (Instant-NGP multires hash grid), 16 levels, F=2, T=2^19,
// N = 2^21 points.
//
// Round-12 = round-11 with (a) two-step voxel-cluster build (dense bf16
// grid first -> cluster assembly from cached reads; replaces 4.1e6 random
// gathers with 0.5e6) and (b) mid_kernel pipelined 2-deep with
// sched_barrier pins (mid's issue is branch-free single-BB, unlike
// fine's, so the r9 wall-defeat doesn't apply).
//
// Machine model (r6/r9/r10/r11 converged): divergent-gather ceiling
// ~0.55 req/cyc/CU. fine = 54 req/pt -> 336us predicted, 340 measured.
//
//   pass 0 : pack f32 tables -> bf16x2 (levels 7-15 only).
//   pass 0b: dense tables levels 0-2 (LDS source); dense grids D3-6;
//            voxel-cluster tables V3-6 assembled from D.
//   pass A : levels 0-2 via LDS-staged dense tables.
//   pass B : levels 3-6 via voxel clusters (2 req / 1 line per pt/level).
//   pass C : levels 7-15 hashed, level-at-a-time, paired (round-9 form).
//   pass 2 : transpose level-major bf16x2 -> [N][32] f32.

constexpr int kLevels = 16;
constexpr int kPoints = 1 << 21;
constexpr uint32_t kTableSize = 1u << 19;
constexpr uint32_t kMask = kTableSize - 1u;
constexpr size_t kPackedBytes = (size_t)kLevels * kTableSize * 4;  // 32 MB
constexpr size_t kLvlOutBytes = (size_t)kLevels * kPoints * 4;     // 128 MB

typedef float f32x4 __attribute__((ext_vector_type(4)));
typedef uint32_t u32x4 __attribute__((ext_vector_type(4)));

// dense coarse (levels 0-2): entry counts and bases (uint32 units)
constexpr int kS0 = 17, kS1 = 21, kS2 = 26;            // res+1
constexpr int kN0 = kS0 * kS0 * kS0;                   // 4913
constexpr int kN1 = kS1 * kS1 * kS1;                   // 9261
constexpr int kN2 = kS2 * kS2 * kS2;                   // 17576
constexpr int kB1 = kN0, kB2 = kN0 + kN1;              // 4913, 14174
constexpr int kNDense = kN0 + kN1 + kN2;               // 31750

// voxel-cluster tables (levels 3-6): S^3 slots x 32B, S = res+1
constexpr int kV3n = 33 * 33 * 33;   // 35937
constexpr int kV4n = 41 * 41 * 41;   // 68921
constexpr int kV5n = 51 * 51 * 51;   // 132651
constexpr int kV6n = 65 * 65 * 65;   // 274625
constexpr int kVTot = kV3n + kV4n + kV5n + kV6n;       // 512134
// byte offsets inside ws (all scratch in freed packed[0..6] region, 14 MB)
constexpr size_t kV3Base = 131072;                         // after dense012
constexpr size_t kV4Base = kV3Base + (size_t)kV3n * 32;    // 1281056
constexpr size_t kV5Base = kV4Base + (size_t)kV4n * 32;    // 3486528
// V5 end = 7731360. V6 (8.8MB) lives in lvl_out slice 7 (+0.4MB of 8):
// written by build, read by mid, clobbered later by fine (stream order).
constexpr size_t kV6Base = kPackedBytes + (size_t)7 * kPoints * 4;
// dense bf16x2 grids D3-6 (S^3 x 4B), after V5:
constexpr size_t kD3Base = 7731456;                        // 256-aligned
constexpr size_t kD4Base = 7875328;   // D3 end 7875204
constexpr size_t kD5Base = 8151296;   // D4 end 8151012
constexpr size_t kD6Base = 8681984;   // D5 end 8681900
// D6 end = 9780484 < 14680064 (freed packed region). OK.

// floor(16 * b^i), b = exp(ln(32)/15) in f64 (boundary levels round up).
__constant__ float c_res[kLevels] = {
    16.f, 20.f, 25.f, 32.f, 40.f, 50.f, 64.f, 80.f,
    101.f, 128.f, 161.f, 203.f, 256.f, 322.f, 406.f, 512.f};

__device__ __forceinline__ uint32_t bf16_rtne_hi(float f) {
    uint32_t u = __float_as_uint(f);
    return (u + 0x7FFFu + ((u >> 16) & 1u)) >> 16;
}
__device__ __forceinline__ float bflo(uint32_t e) {
    return __uint_as_float(e << 16);
}
__device__ __forceinline__ float bfhi(uint32_t e) {
    return __uint_as_float(e & 0xFFFF0000u);
}

// ------- pass 0: pack tables to bf16x2 (levels 7-15 only, main path) ----
__global__ __launch_bounds__(256) void pack_tables_kernel(
    const float* __restrict__ tables, uint32_t* __restrict__ packed, int base)
{
    const int i = base + blockIdx.x * 256 + threadIdx.x;  // 2 entries/thread
    const f32x4 v = reinterpret_cast<const f32x4*>(tables)[i];
    uint2 o;
    o.x = bf16_rtne_hi(v.x) | (bf16_rtne_hi(v.y) << 16);
    o.y = bf16_rtne_hi(v.z) | (bf16_rtne_hi(v.w) << 16);
    reinterpret_cast<uint2*>(packed)[i] = o;
}

// ---------------- pass 0b-1: dense de-hashed tables, levels 0-2 --------
template <int S, int LVL>
__device__ __forceinline__ void build_dense_one(
    int r, const float* __restrict__ tables, uint32_t* __restrict__ dst)
{
    const int bz = r % S;
    const int t = r / S;
    const int by = t % S;
    const int bx = t / S;
    const uint32_t h = ((uint32_t)bx ^ ((uint32_t)by * 2654435761u) ^
                        ((uint32_t)bz * 805459861u)) & kMask;
    const float2 src = *reinterpret_cast<const float2*>(
        tables + (((size_t)LVL << 19) + h) * 2);
    dst[r] = bf16_rtne_hi(src.x) | (bf16_rtne_hi(src.y) << 16);
}

__global__ __launch_bounds__(256) void build_dense012_kernel(
    const float* __restrict__ tables, uint32_t* __restrict__ dense)
{
    const int idx = blockIdx.x * 256 + threadIdx.x;
    if (idx >= kNDense) return;
    if (idx < kB1)      build_dense_one<kS0, 0>(idx,       tables, dense);
    else if (idx < kB2) build_dense_one<kS1, 1>(idx - kB1, tables, dense + kB1);
    else                build_dense_one<kS2, 2>(idx - kB2, tables, dense + kB2);
}

// --------- pass 0b-2a: dense bf16x2 grids D3-6 (1 gather per corner) ----
__global__ __launch_bounds__(256) void build_denseD_kernel(
    const float* __restrict__ tables, char* __restrict__ ws)
{
    const int g = blockIdx.x * 256 + threadIdx.x;
    if (g >= kVTot) return;
    if (g < kV3n)
        build_dense_one<33, 3>(g, tables, (uint32_t*)(ws + kD3Base));
    else if (g < kV3n + kV4n)
        build_dense_one<41, 4>(g - kV3n, tables, (uint32_t*)(ws + kD4Base));
    else if (g < kV3n + kV4n + kV5n)
        build_dense_one<51, 5>(g - kV3n - kV4n, tables,
                               (uint32_t*)(ws + kD5Base));
    else
        build_dense_one<65, 6>(g - kV3n - kV4n - kV5n, tables,
                               (uint32_t*)(ws + kD6Base));
}

// --------- pass 0b-2b: assemble voxel clusters from D (cached reads) ----
// V[(bx*S+by)*S+bz] = 8 corners, c = (dx<<2)|(dy<<1)|dz. Corner coords
// clamped to S-1 (voxels with bx==res never evaluated; clamp avoids OOB).
template <int S>
__device__ __forceinline__ void build_vox_one(
    int v, const uint32_t* __restrict__ D, u32x4* __restrict__ dst)
{
    const int bz = v % S;
    const int t = v / S;
    const int by = t % S;
    const int bx = t / S;
    const int x1 = (bx + 1 < S) ? bx + 1 : S - 1;
    const int y1 = (by + 1 < S) ? by + 1 : S - 1;
    const int z1 = (bz + 1 < S) ? bz + 1 : S - 1;
    u32x4 q0, q1;
    q0.x = D[(bx * S + by) * S + bz];
    q0.y = D[(bx * S + by) * S + z1];
    q0.z = D[(bx * S + y1) * S + bz];
    q0.w = D[(bx * S + y1) * S + z1];
    q1.x = D[(x1 * S + by) * S + bz];
    q1.y = D[(x1 * S + by) * S + z1];
    q1.z = D[(x1 * S + y1) * S + bz];
    q1.w = D[(x1 * S + y1) * S + z1];
    dst[2 * v + 0] = q0;
    dst[2 * v + 1] = q1;
}

__global__ __launch_bounds__(256) void build_vox_kernel(char* __restrict__ ws)
{
    const int v = blockIdx.x * 256 + threadIdx.x;
    if (v >= kVTot) return;
    if (v < kV3n)
        build_vox_one<33>(v, (const uint32_t*)(ws + kD3Base),
                          (u32x4*)(ws + kV3Base));
    else if (v < kV3n + kV4n)
        build_vox_one<41>(v - kV3n, (const uint32_t*)(ws + kD4Base),
                          (u32x4*)(ws + kV4Base));
    else if (v < kV3n + kV4n + kV5n)
        build_vox_one<51>(v - kV3n - kV4n, (const uint32_t*)(ws + kD5Base),
                          (u32x4*)(ws + kV5Base));
    else
        build_vox_one<65>(v - kV3n - kV4n - kV5n,
                          (const uint32_t*)(ws + kD6Base),
                          (u32x4*)(ws + kV6Base));
}

// ---------------- pass A: levels 0-2 via LDS dense tables ----------------
template <int S, int BASE, int LVL>
__device__ __forceinline__ void eval_coarse(
    const uint32_t* __restrict__ lds, float px, float py, float pz, float r,
    uint32_t* __restrict__ lvl_out, int n)
{
    const float tx = px * r, ty = py * r, tz = pz * r;
    const float fx = floorf(tx), fy = floorf(ty), fz = floorf(tz);
    const int bx = (int)fx, by = (int)fy, bz = (int)fz;
    const float rx = tx - fx, ry = ty - fy, rz = tz - fz;
    const int c = BASE + (bx * S + by) * S + bz;
    const uint32_t e000 = lds[c],             e001 = lds[c + 1];
    const uint32_t e010 = lds[c + S],         e011 = lds[c + S + 1];
    const uint32_t e100 = lds[c + S * S],     e101 = lds[c + S * S + 1];
    const uint32_t e110 = lds[c + S * S + S], e111 = lds[c + S * S + S + 1];
    const float wx1 = rx, wx0 = 1.f - rx;
    const float wy1 = ry, wy0 = 1.f - ry;
    const float wz1 = rz, wz0 = 1.f - rz;
    float a0 = 0.f, a1 = 0.f;
    a0 = fmaf(wx0 * wy0 * wz0, bflo(e000), a0);
    a1 = fmaf(wx0 * wy0 * wz0, bfhi(e000), a1);
    a0 = fmaf(wx0 * wy0 * wz1, bflo(e001), a0);
    a1 = fmaf(wx0 * wy0 * wz1, bfhi(e001), a1);
    a0 = fmaf(wx0 * wy1 * wz0, bflo(e010), a0);
    a1 = fmaf(wx0 * wy1 * wz0, bfhi(e010), a1);
    a0 = fmaf(wx0 * wy1 * wz1, bflo(e011), a0);
    a1 = fmaf(wx0 * wy1 * wz1, bfhi(e011), a1);
    a0 = fmaf(wx1 * wy0 * wz0, bflo(e100), a0);
    a1 = fmaf(wx1 * wy0 * wz0, bfhi(e100), a1);
    a0 = fmaf(wx1 * wy0 * wz1, bflo(e101), a0);
    a1 = fmaf(wx1 * wy0 * wz1, bfhi(e101), a1);
    a0 = fmaf(wx1 * wy1 * wz0, bflo(e110), a0);
    a1 = fmaf(wx1 * wy1 * wz0, bfhi(e110), a1);
    a0 = fmaf(wx1 * wy1 * wz1, bflo(e111), a0);
    a1 = fmaf(wx1 * wy1 * wz1, bfhi(e111), a1);
    lvl_out[(size_t)LVL * kPoints + n] =
        bf16_rtne_hi(a0) | (bf16_rtne_hi(a1) << 16);
}

__global__ __launch_bounds__(512) void coarse_kernel(
    const float* __restrict__ x, const uint32_t* __restrict__ dense,
    uint32_t* __restrict__ lvl_out)
{
    __shared__ uint32_t s_tab[kNDense];  // 127000 B
    for (int i = threadIdx.x; i < kNDense; i += 512) s_tab[i] = dense[i];
    __syncthreads();

    const int n0 = blockIdx.x * 2048 + threadIdx.x;
#pragma unroll
    for (int k = 0; k < 4; ++k) {
        const int n = n0 + k * 512;
        const float px = fminf(fmaxf(x[3 * n + 0], 0.0f), 1.0f);
        const float py = fminf(fmaxf(x[3 * n + 1], 0.0f), 1.0f);
        const float pz = fminf(fmaxf(x[3 * n + 2], 0.0f), 1.0f);
        eval_coarse<kS0, 0,   0>(s_tab, px, py, pz, 16.f, lvl_out, n);
        eval_coarse<kS1, kB1, 1>(s_tab, px, py, pz, 20.f, lvl_out, n);
        eval_coarse<kS2, kB2, 2>(s_tab, px, py, pz, 25.f, lvl_out, n);
    }
}

// ------- pass B: levels 3-6 via voxel clusters, pinned 2-deep pipe ------
struct MidSt {
    float rx, ry, rz;
    u32x4 q0, q1;      // 8 corner entries (c = (dx<<2)|(dy<<1)|dz)
};

template <int R>
__device__ __forceinline__ void issue_mid(
    MidSt& st, const u32x4* __restrict__ V, float px, float py, float pz)
{
    const float r = (float)R;
    const float tx = px * r, ty = py * r, tz = pz * r;
    const float fx = floorf(tx), fy = floorf(ty), fz = floorf(tz);
    const int bx = (int)fx, by = (int)fy, bz = (int)fz;
    st.rx = tx - fx;  st.ry = ty - fy;  st.rz = tz - fz;
    constexpr int S = R + 1;
    const int idx = (bx * S + by) * S + bz;
    st.q0 = V[2 * idx + 0];
    st.q1 = V[2 * idx + 1];
}

__device__ __forceinline__ void consume_mid(
    const MidSt& st, uint32_t* __restrict__ dst)
{
    const float wx1 = st.rx, wx0 = 1.f - st.rx;
    const float wy1 = st.ry, wy0 = 1.f - st.ry;
    const float wz1 = st.rz, wz0 = 1.f - st.rz;
    float a0 = 0.f, a1 = 0.f;
    a0 = fmaf(wx0 * wy0 * wz0, bflo(st.q0.x), a0);
    a1 = fmaf(wx0 * wy0 * wz0, bfhi(st.q0.x), a1);
    a0 = fmaf(wx0 * wy0 * wz1, bflo(st.q0.y), a0);
    a1 = fmaf(wx0 * wy0 * wz1, bfhi(st.q0.y), a1);
    a0 = fmaf(wx0 * wy1 * wz0, bflo(st.q0.z), a0);
    a1 = fmaf(wx0 * wy1 * wz0, bfhi(st.q0.z), a1);
    a0 = fmaf(wx0 * wy1 * wz1, bflo(st.q0.w), a0);
    a1 = fmaf(wx0 * wy1 * wz1, bfhi(st.q0.w), a1);
    a0 = fmaf(wx1 * wy0 * wz0, bflo(st.q1.x), a0);
    a1 = fmaf(wx1 * wy0 * wz0, bfhi(st.q1.x), a1);
    a0 = fmaf(wx1 * wy0 * wz1, bflo(st.q1.y), a0);
    a1 = fmaf(wx1 * wy0 * wz1, bfhi(st.q1.y), a1);
    a0 = fmaf(wx1 * wy1 * wz0, bflo(st.q1.z), a0);
    a1 = fmaf(wx1 * wy1 * wz0, bfhi(st.q1.z), a1);
    a0 = fmaf(wx1 * wy1 * wz1, bflo(st.q1.w), a0);
    a1 = fmaf(wx1 * wy1 * wz1, bfhi(st.q1.w), a1);
    *dst = bf16_rtne_hi(a0) | (bf16_rtne_hi(a1) << 16);
}

template <int R, int LVL>
__device__ __forceinline__ void mid_level(
    const float* __restrict__ x, const u32x4* __restrict__ V,
    uint32_t* __restrict__ lvl_out, int n0)
{
    uint32_t* __restrict__ w = lvl_out + (size_t)LVL * kPoints;
    const float px0 = fminf(fmaxf(x[3 * (n0 + 0 * 256) + 0], 0.f), 1.f);
    const float py0 = fminf(fmaxf(x[3 * (n0 + 0 * 256) + 1], 0.f), 1.f);
    const float pz0 = fminf(fmaxf(x[3 * (n0 + 0 * 256) + 2], 0.f), 1.f);
    const float px1 = fminf(fmaxf(x[3 * (n0 + 1 * 256) + 0], 0.f), 1.f);
    const float py1 = fminf(fmaxf(x[3 * (n0 + 1 * 256) + 1], 0.f), 1.f);
    const float pz1 = fminf(fmaxf(x[3 * (n0 + 1 * 256) + 2], 0.f), 1.f);
    const float px2 = fminf(fmaxf(x[3 * (n0 + 2 * 256) + 0], 0.f), 1.f);
    const float py2 = fminf(fmaxf(x[3 * (n0 + 2 * 256) + 1], 0.f), 1.f);
    const float pz2 = fminf(fmaxf(x[3 * (n0 + 2 * 256) + 2], 0.f), 1.f);
    const float px3 = fminf(fmaxf(x[3 * (n0 + 3 * 256) + 0], 0.f), 1.f);
    const float py3 = fminf(fmaxf(x[3 * (n0 + 3 * 256) + 1], 0.f), 1.f);
    const float pz3 = fminf(fmaxf(x[3 * (n0 + 3 * 256) + 2], 0.f), 1.f);
    __builtin_amdgcn_sched_barrier(0);

    MidSt A, B;
    issue_mid<R>(A, V, px0, py0, pz0);
    issue_mid<R>(B, V, px1, py1, pz1);
    __builtin_amdgcn_sched_barrier(0);
    consume_mid(A, &w[n0 + 0 * 256]);
    __builtin_amdgcn_sched_barrier(0);
    issue_mid<R>(A, V, px2, py2, pz2);
    __builtin_amdgcn_sched_barrier(0);
    consume_mid(B, &w[n0 + 1 * 256]);
    __builtin_amdgcn_sched_barrier(0);
    issue_mid<R>(B, V, px3, py3, pz3);
    __builtin_amdgcn_sched_barrier(0);
    consume_mid(A, &w[n0 + 2 * 256]);
    __builtin_amdgcn_sched_barrier(0);
    consume_mid(B, &w[n0 + 3 * 256]);
}

__global__ __launch_bounds__(256) void mid_kernel(
    const float* __restrict__ x, const char* __restrict__ ws,
    uint32_t* __restrict__ lvl_out)
{
    const int b = blockIdx.x;
    const int sub = b >> 11;                 // 0..3 -> level 3..6
    const int chunk = b & 2047;
    const int n0 = chunk * 1024 + threadIdx.x;
    if (sub == 0)
        mid_level<32, 3>(x, (const u32x4*)(ws + kV3Base), lvl_out, n0);
    else if (sub == 1)
        mid_level<40, 4>(x, (const u32x4*)(ws + kV4Base), lvl_out, n0);
    else if (sub == 2)
        mid_level<50, 5>(x, (const u32x4*)(ws + kV5Base), lvl_out, n0);
    else
        mid_level<64, 6>(x, (const u32x4*)(ws + kV6Base), lvl_out, n0);
}

// ------- pass C: levels 7-15 hashed, pinned 2-deep pipeline (round 9) ---
struct PtSt {
    float rx, ry, rz;
    uint32_t sel;              // bit j = half-selector for corner pair j
    uint2 p0, p1, p2, p3;      // corner-pair entries (elo/ehi encoded)
};

__device__ __forceinline__ void issue_pt(
    PtSt& st, const float* __restrict__ x, int n, float r,
    const uint32_t* __restrict__ tab)
{
    const float px = fminf(fmaxf(x[3 * n + 0], 0.f), 1.f);
    const float py = fminf(fmaxf(x[3 * n + 1], 0.f), 1.f);
    const float pz = fminf(fmaxf(x[3 * n + 2], 0.f), 1.f);
    const float tx = px * r, ty = py * r, tz = pz * r;
    const float fx = floorf(tx), fy = floorf(ty), fz = floorf(tz);
    const int bx = (int)fx, by = (int)fy, bz = (int)fz;
    st.rx = tx - fx;  st.ry = ty - fy;  st.rz = tz - fz;
    const uint32_t hy0 = (uint32_t)by * 2654435761u;
    const uint32_t hy1 = (uint32_t)(by + 1) * 2654435761u;
    const uint32_t hz0 = (uint32_t)bz * 805459861u;
    const uint32_t hz1 = (uint32_t)(bz + 1) * 805459861u;
    const uint32_t bxu = (uint32_t)bx, bx1 = bxu + 1u;
    const uint32_t m0 = hy0 ^ hz0, m1 = hy0 ^ hz1;
    const uint32_t m2 = hy1 ^ hz0, m3 = hy1 ^ hz1;
    if ((bx & 1) == 0) {
        const uint32_t h0 = (bxu ^ m0) & kMask;
        const uint32_t h1 = (bxu ^ m1) & kMask;
        const uint32_t h2 = (bxu ^ m2) & kMask;
        const uint32_t h3 = (bxu ^ m3) & kMask;
        st.sel = (h0 & 1u) | ((h1 & 1u) << 1) |
                 ((h2 & 1u) << 2) | ((h3 & 1u) << 3);
        st.p0 = *reinterpret_cast<const uint2*>(tab + (h0 & ~1u));
        st.p1 = *reinterpret_cast<const uint2*>(tab + (h1 & ~1u));
        st.p2 = *reinterpret_cast<const uint2*>(tab + (h2 & ~1u));
        st.p3 = *reinterpret_cast<const uint2*>(tab + (h3 & ~1u));
    } else {
        st.sel = 0u;
        st.p0.x = tab[(bxu ^ m0) & kMask];  st.p0.y = tab[(bx1 ^ m0) & kMask];
        st.p1.x = tab[(bxu ^ m1) & kMask];  st.p1.y = tab[(bx1 ^ m1) & kMask];
        st.p2.x = tab[(bxu ^ m2) & kMask];  st.p2.y = tab[(bx1 ^ m2) & kMask];
        st.p3.x = tab[(bxu ^ m3) & kMask];  st.p3.y = tab[(bx1 ^ m3) & kMask];
    }
}

__device__ __forceinline__ void consume_pt(
    const PtSt& st, uint32_t* __restrict__ w, int n)
{
    const float wx1 = st.rx, wx0 = 1.f - st.rx;
    const float wy1 = st.ry, wy0 = 1.f - st.ry;
    const float wz1 = st.rz, wz0 = 1.f - st.rz;
    const float w0 = wy0 * wz0, w1 = wy0 * wz1;
    const float w2 = wy1 * wz0, w3 = wy1 * wz1;
    const uint32_t e0 = (st.sel & 1u) ? st.p0.y : st.p0.x;
    const uint32_t f0 = (st.sel & 1u) ? st.p0.x : st.p0.y;
    const uint32_t e1 = (st.sel & 2u) ? st.p1.y : st.p1.x;
    const uint32_t f1 = (st.sel & 2u) ? st.p1.x : st.p1.y;
    const uint32_t e2 = (st.sel & 4u) ? st.p2.y : st.p2.x;
    const uint32_t f2 = (st.sel & 4u) ? st.p2.x : st.p2.y;
    const uint32_t e3 = (st.sel & 8u) ? st.p3.y : st.p3.x;
    const uint32_t f3 = (st.sel & 8u) ? st.p3.x : st.p3.y;
    float a0 = 0.f, a1 = 0.f;
    a0 = fmaf(w0, fmaf(wx0, bflo(e0), wx1 * bflo(f0)), a0);
    a1 = fmaf(w0, fmaf(wx0, bfhi(e0), wx1 * bfhi(f0)), a1);
    a0 = fmaf(w1, fmaf(wx0, bflo(e1), wx1 * bflo(f1)), a0);
    a1 = fmaf(w1, fmaf(wx0, bfhi(e1), wx1 * bfhi(f1)), a1);
    a0 = fmaf(w2, fmaf(wx0, bflo(e2), wx1 * bflo(f2)), a0);
    a1 = fmaf(w2, fmaf(wx0, bfhi(e2), wx1 * bfhi(f2)), a1);
    a0 = fmaf(w3, fmaf(wx0, bflo(e3), wx1 * bflo(f3)), a0);
    a1 = fmaf(w3, fmaf(wx0, bfhi(e3), wx1 * bfhi(f3)), a1);
    w[n] = bf16_rtne_hi(a0) | (bf16_rtne_hi(a1) << 16);
}

__global__ __launch_bounds__(256) void fine_kernel(
    const float* __restrict__ x,
    const uint32_t* __restrict__ packed,
    uint32_t* __restrict__ lvl_out)
{
    const int b = blockIdx.x;
    const int level = 7 + (b >> 11);       // level-at-a-time machine fill
    const int chunk = b & 2047;

    const float r = c_res[level];
    const uint32_t* __restrict__ tab = packed + (size_t)level * kTableSize;
    uint32_t* __restrict__ w = lvl_out + (size_t)level * kPoints;

    const int n0 = chunk * 1024 + threadIdx.x;

    PtSt A, B;
    issue_pt(A, x, n0 + 0 * 256, r, tab);
    issue_pt(B, x, n0 + 1 * 256, r, tab);
    __builtin_amdgcn_sched_barrier(0);
    consume_pt(A, w, n0 + 0 * 256);
    __builtin_amdgcn_sched_barrier(0);
    issue_pt(A, x, n0 + 2 * 256, r, tab);
    __builtin_amdgcn_sched_barrier(0);
    consume_pt(B, w, n0 + 1 * 256);
    __builtin_amdgcn_sched_barrier(0);
    issue_pt(B, x, n0 + 3 * 256, r, tab);
    __builtin_amdgcn_sched_barrier(0);
    consume_pt(A, w, n0 + 2 * 256);
    __builtin_amdgcn_sched_barrier(0);
    consume_pt(B, w, n0 + 3 * 256);
}

// ---------------- pass 2: level-major bf16 -> [N][32] f32 ----------------
__global__ __launch_bounds__(256) void untile_kernel(
    const uint32_t* __restrict__ lvl_out, float* __restrict__ out)
{
    const int n = blockIdx.x * 256 + threadIdx.x;
    float vals[2 * kLevels];
#pragma unroll
    for (int l = 0; l < kLevels; ++l) {
        const uint32_t u = lvl_out[(size_t)l * kPoints + n];
        vals[2 * l + 0] = bflo(u);
        vals[2 * l + 1] = bfhi(u);
    }
    float4* o4 = reinterpret_cast<float4*>(out + (size_t)n * (2 * kLevels));
#pragma unroll
    for (int kq = 0; kq < 8; ++kq) {
        o4[kq] = make_float4(vals[4 * kq + 0], vals[4 * kq + 1],
                             vals[4 * kq + 2], vals[4 * kq + 3]);
    }
}

// ---------------- fallbacks (round-0/round-2 proven paths) --------------
__device__ __forceinline__ void eval_level(
    float px, float py, float pz, float r,
    const uint32_t* __restrict__ tab, float& a0, float& a1)
{
    const float tx = px * r, ty = py * r, tz = pz * r;
    const float fx = floorf(tx), fy = floorf(ty), fz = floorf(tz);
    const int bx = (int)fx, by = (int)fy, bz = (int)fz;
    const float rx = tx - fx, ry = ty - fy, rz = tz - fz;

    const uint32_t hx0 = (uint32_t)bx;
    const uint32_t hx1 = (uint32_t)(bx + 1);
    const uint32_t hy0 = (uint32_t)by * 2654435761u;
    const uint32_t hy1 = (uint32_t)(by + 1) * 2654435761u;
    const uint32_t hz0 = (uint32_t)bz * 805459861u;
    const uint32_t hz1 = (uint32_t)(bz + 1) * 805459861u;

    const float wx1 = rx, wx0 = 1.0f - rx;
    const float wy1 = ry, wy0 = 1.0f - ry;
    const float wz1 = rz, wz0 = 1.0f - rz;

    a0 = 0.0f; a1 = 0.0f;
#pragma unroll
    for (int c = 0; c < 8; ++c) {
        const uint32_t h = (((c & 4) ? hx1 : hx0) ^
                            ((c & 2) ? hy1 : hy0) ^
                            ((c & 1) ? hz1 : hz0)) & kMask;
        const uint32_t e = tab[h];
        const float w = ((c & 4) ? wx1 : wx0) *
                        ((c & 2) ? wy1 : wy0) *
                        ((c & 1) ? wz1 : wz0);
        a0 = fmaf(w, bflo(e), a0);
        a1 = fmaf(w, bfhi(e), a1);
    }
}

__global__ __launch_bounds__(256) void direct_kernel(
    const float* __restrict__ x,
    const float* __restrict__ tables,
    float* __restrict__ out)
{
    const int n = blockIdx.x * 256 + threadIdx.x;
    float px = fminf(fmaxf(x[3 * n + 0], 0.0f), 1.0f);
    float py = fminf(fmaxf(x[3 * n + 1], 0.0f), 1.0f);
    float pz = fminf(fmaxf(x[3 * n + 2], 0.0f), 1.0f);

    const float res_tab[kLevels] = {
        16.f, 20.f, 25.f, 32.f, 40.f, 50.f, 64.f, 80.f,
        101.f, 128.f, 161.f, 203.f, 256.f, 322.f, 406.f, 512.f};

    float acc[2 * kLevels];
#pragma unroll
    for (int l = 0; l < kLevels; ++l) {
        const float r = res_tab[l];
        const float tx = px * r, ty = py * r, tz = pz * r;
        const float fx = floorf(tx), fy = floorf(ty), fz = floorf(tz);
        const int bx = (int)fx, by = (int)fy, bz = (int)fz;
        const float rx = tx - fx, ry = ty - fy, rz = tz - fz;
        const uint32_t hx0 = (uint32_t)bx;
        const uint32_t hx1 = (uint32_t)(bx + 1);
        const uint32_t hy0 = (uint32_t)by * 2654435761u;
        const uint32_t hy1 = (uint32_t)(by + 1) * 2654435761u;
        const uint32_t hz0 = (uint32_t)bz * 805459861u;
        const uint32_t hz1 = (uint32_t)(bz + 1) * 805459861u;
        const float wx1 = rx, wx0 = 1.0f - rx;
        const float wy1 = ry, wy0 = 1.0f - ry;
        const float wz1 = rz, wz0 = 1.0f - rz;
        const float2* __restrict__ tab =
            reinterpret_cast<const float2*>(tables) + (size_t)l * kTableSize;
        float a0 = 0.0f, a1 = 0.0f;
#pragma unroll
        for (int c = 0; c < 8; ++c) {
            const uint32_t h = (((c & 4) ? hx1 : hx0) ^
                                ((c & 2) ? hy1 : hy0) ^
                                ((c & 1) ? hz1 : hz0)) & kMask;
            const float2 e = tab[h];
            const float w = ((c & 4) ? wx1 : wx0) *
                            ((c & 2) ? wy1 : wy0) *
                            ((c & 1) ? wz1 : wz0);
            a0 = fmaf(w, e.x, a0);
            a1 = fmaf(w, e.y, a1);
        }
        acc[2 * l + 0] = a0;
        acc[2 * l + 1] = a1;
    }
    float4* o4 = reinterpret_cast<float4*>(out + (size_t)n * (2 * kLevels));
#pragma unroll
    for (int kq = 0; kq < 8; ++kq) {
        o4[kq] = make_float4(acc[4 * kq + 0], acc[4 * kq + 1],
                             acc[4 * kq + 2], acc[4 * kq + 3]);
    }
}

__global__ __launch_bounds__(256) void direct_packed_kernel(
    const float* __restrict__ x,
    const uint32_t* __restrict__ packed,
    float* __restrict__ out)
{
    const int n = blockIdx.x * 256 + threadIdx.x;
    float px = fminf(fmaxf(x[3 * n + 0], 0.0f), 1.0f);
    float py = fminf(fmaxf(x[3 * n + 1], 0.0f), 1.0f);
    float pz = fminf(fmaxf(x[3 * n + 2], 0.0f), 1.0f);

    const float res_tab[kLevels] = {
        16.f, 20.f, 25.f, 32.f, 40.f, 50.f, 64.f, 80.f,
        101.f, 128.f, 161.f, 203.f, 256.f, 322.f, 406.f, 512.f};

    float acc[2 * kLevels];
#pragma unroll
    for (int l = 0; l < kLevels; ++l) {
        float a0, a1;
        eval_level(px, py, pz, res_tab[l],
                   packed + (size_t)l * kTableSize, a0, a1);
        acc[2 * l + 0] = a0;
        acc[2 * l + 1] = a1;
    }
    float4* o4 = reinterpret_cast<float4*>(out + (size_t)n * (2 * kLevels));
#pragma unroll
    for (int kq = 0; kq < 8; ++kq) {
        o4[kq] = make_float4(acc[4 * kq + 0], acc[4 * kq + 1],
                             acc[4 * kq + 2], acc[4 * kq + 3]);
    }
}

extern "C" void kernel_launch(void* const* d_in, const int* in_sizes, int n_in,
                              void* d_out, int out_size, void* d_ws, size_t ws_size,
                              hipStream_t stream) {
    const float* x = (const float*)d_in[0];       // [2^21, 3] f32
    const float* tables = (const float*)d_in[1];  // [16, 2^19, 2] f32
    float* out = (float*)d_out;                   // [2^21, 32] f32

    if (ws_size >= kPackedBytes + kLvlOutBytes) {
        char* ws = (char*)d_ws;
        uint32_t* packed = (uint32_t*)ws;
        uint32_t* lvl_out = (uint32_t*)(ws + kPackedBytes);
        uint32_t* dense012 = (uint32_t*)ws;  // overlays packed[0] (unused)

        // pack only levels 7-15 (fine path).
        hipLaunchKernelGGL(pack_tables_kernel,
                           dim3((9 << 19) / 2 / 256), dim3(256),
                           0, stream, tables, packed, (7 << 19) / 2);
        hipLaunchKernelGGL(build_dense012_kernel,
                           dim3((kNDense + 255) / 256), dim3(256),
                           0, stream, tables, dense012);
        // two-step vox build: dense grids D3-6 (1 gather/corner), then
        // cluster assembly from D (cache-local reads).
        hipLaunchKernelGGL(build_denseD_kernel,
                           dim3((kVTot + 255) / 256), dim3(256),
                           0, stream, tables, ws);
        hipLaunchKernelGGL(build_vox_kernel,
                           dim3((kVTot + 255) / 256), dim3(256),
                           0, stream, ws);
        // pass A: levels 0-2 (LDS), 1024 blocks x 512 thr x 4 pts
        hipLaunchKernelGGL(coarse_kernel, dim3(kPoints / 2048), dim3(512),
                           0, stream, x, dense012, lvl_out);
        // pass B: levels 3-6 (voxel clusters, pipelined), 4 x 2048 blocks
        hipLaunchKernelGGL(mid_kernel, dim3(4 * 2048), dim3(256),
                           0, stream, x, (const char*)ws, lvl_out);
        // pass C: levels 7-15 (hashed, pinned 2-deep pipe), 9 x 2048 blocks
        hipLaunchKernelGGL(fine_kernel, dim3(9 * 2048), dim3(256),
                           0, stream, x, packed, lvl_out);
        // pass 2
        hipLaunchKernelGGL(untile_kernel, dim3(kPoints / 256), dim3(256),
                           0, stream, lvl_out, out);
    } else if (ws_size >= kPackedBytes) {
        uint32_t* packed = (uint32_t*)d_ws;
        hipLaunchKernelGGL(pack_tables_kernel,
                           dim3((kLevels * kTableSize / 2) / 256), dim3(256),
                           0, stream, tables, packed, 0);
        hipLaunchKernelGGL(direct_packed_kernel, dim3(kPoints / 256), dim3(256),
                           0, stream, x, packed, out);
    } else {
        hipLaunchKernelGGL(direct_kernel, dim3(kPoints / 256), dim3(256),
                           0, stream, x, tables, out);
    }
}